// Round 7
// baseline (178.416 us; speedup 1.0000x reference)
//
#include <hip/hip_runtime.h>
#include <stdint.h>

#define S_LEN 4096
#define HDIM  768
#define NHEAD 12
#define DHEAD 64

typedef _Float16 f16;
typedef __attribute__((ext_vector_type(8)))  _Float16 f16x8;
typedef __attribute__((ext_vector_type(4)))  _Float16 f16x4;
typedef __attribute__((ext_vector_type(4)))  float    f32x4;
typedef __attribute__((ext_vector_type(16))) float    f32x16;

typedef __attribute__((address_space(1))) void gv_t;
typedef __attribute__((address_space(3))) void lv_t;

__device__ __forceinline__ void async_copy16(const void* g, void* l) {
  __builtin_amdgcn_global_load_lds((gv_t*)g, (lv_t*)l, 16, 0, 0);
}

__device__ __forceinline__ float fast_exp2(float x) {
#if __has_builtin(__builtin_amdgcn_exp2f)
  return __builtin_amdgcn_exp2f(x);
#else
  return exp2f(x);
#endif
}

__device__ __forceinline__ int swz4(int row) { return (row ^ (row >> 2)) & 3; }

// ---------------- workspace layout (heavy reuse) ----------------
constexpr size_t OFF_META = 0;                          // int kcount
constexpr size_t OFF_RIDX = 256;                        // int[4096] inverse map p->s
constexpr size_t OFF_XB   = 65536;                      // f16 x[4096*768]
constexpr size_t SZ_XB    = (size_t)S_LEN * HDIM * 2;
constexpr size_t OFF_WQKV = OFF_XB + SZ_XB;             // f16[3*768*768]; later PL
constexpr size_t SZ_WQKV  = (size_t)3 * HDIM * HDIM * 2;
constexpr size_t OFF_WO   = OFF_WQKV + SZ_WQKV;         // f16[768*768]
constexpr size_t SZ_WO    = (size_t)HDIM * HDIM * 2;
constexpr size_t OFF_Q    = OFF_WO + SZ_WO;             // f16[12][4096][64]
constexpr size_t SZ_HD    = (size_t)NHEAD * S_LEN * DHEAD * 2;
constexpr size_t OFF_K    = OFF_Q + SZ_HD;              // f16[12][4096][64] compacted
constexpr size_t OFF_VT   = OFF_K + SZ_HD;              // f16[12][64][4096] transposed+permuted V
constexpr size_t OFF_VR   = OFF_VT + SZ_HD;             // f16[12][4096][64] V rows; later PO split0
constexpr size_t OFF_PO1  = OFF_VR + SZ_HD;             // f16[12][4096][64] PO split1

// ---------------- prep: fp32->fp16 convert + mask compaction (inverse map) ----------------
__global__ __launch_bounds__(256) void k_prep(const float* __restrict__ x,
                                              const float* __restrict__ wq,
                                              const float* __restrict__ wk,
                                              const float* __restrict__ wv,
                                              const float* __restrict__ wo,
                                              const int* __restrict__ mi,
                                              f16* __restrict__ dst,
                                              int* __restrict__ ridx,
                                              int* __restrict__ meta) {
  __shared__ int s_flag;
  __shared__ int s_cnt[256];
  const int b = blockIdx.x, tid = threadIdx.x;
  if (b < 5376) {
    int i = b * 256 + tid;                   // 1376256 float4 units
    const float* src; int off;
    if (i < 786432) { src = x; off = i; }
    else {
      int j = i - 786432;
      int w = j / 147456;
      off = j - w * 147456;
      src = (w == 0) ? wq : (w == 1) ? wk : (w == 2) ? wv : wo;
    }
    float4 v = ((const float4*)src)[off];
    f16x4 h;
    h[0] = (f16)v.x; h[1] = (f16)v.y; h[2] = (f16)v.z; h[3] = (f16)v.w;
    ((f16x4*)dst)[i] = h;
    return;
  }
  // ---- mask block ----
  if (tid == 0) s_flag = 1;
  __syncthreads();
  int bad = 0;
  #pragma unroll
  for (int k = 0; k < 4; ++k) {
    int v = mi[k * 256 + tid];
    if (v != 0 && v != 1) bad = 1;
  }
  if (bad) atomicAnd(&s_flag, 0);
  __syncthreads();
  const int isInt = s_flag;
  const unsigned char* mu8 = (const unsigned char*)mi;
  int keep[16]; int cnt = 0;
  const int s0 = tid * 16;
  #pragma unroll
  for (int k = 0; k < 16; ++k) {
    int mval = isInt ? mi[s0 + k] : (int)mu8[s0 + k];
    keep[k] = (mval == 0) ? 1 : 0;           // True => masked out (excluded)
    cnt += keep[k];
    ridx[s0 + k] = 0;                        // zero-fill inverse map (pad-safe)
  }
  s_cnt[tid] = cnt;
  __syncthreads();
  for (int off = 1; off < 256; off <<= 1) {
    int t = (tid >= off) ? s_cnt[tid - off] : 0;
    __syncthreads();
    s_cnt[tid] += t;
    __syncthreads();
  }
  int base = s_cnt[tid] - cnt;               // exclusive prefix
  #pragma unroll
  for (int k = 0; k < 16; ++k) {
    if (keep[k]) { ridx[base] = s0 + k; ++base; }
  }
  if (tid == 255) meta[0] = s_cnt[255];
}

// ---------------- fused QKV projection GEMM (32x32x16 MFMA, compacted K/V rows) ---------
__global__ __launch_bounds__(256) void k_qkv(
    const f16* __restrict__ xb, const f16* __restrict__ wqkv,
    const float* __restrict__ bq, const float* __restrict__ bk, const float* __restrict__ bv,
    const int* __restrict__ ridx, const int* __restrict__ meta,
    f16* __restrict__ Qh, f16* __restrict__ Kc, f16* __restrict__ Vrow) {
  __shared__ __attribute__((aligned(16))) f16 lA[128 * 32];
  __shared__ __attribute__((aligned(16))) f16 lB[128 * 32];
  const int tid = threadIdx.x;
  const int wid = tid >> 6, lane = tid & 63;
  const int hf = lane >> 5, l31 = lane & 31;
  const int wm = wid >> 1, wn = wid & 1;
  const int tn = blockIdx.x;
  const int m0 = blockIdx.y * 128;
  const int mat = tn / 6;
  const int nb = (tn % 6) * 128;
  const int kc = meta[0];
  if (mat != 0 && m0 >= kc) return;          // fully-pad K/V tile
  const f16* wbase = wqkv + (size_t)mat * HDIM * HDIM;

  const int ar0 = tid >> 2, ar1 = 64 + (tid >> 2);
  const f16* asrc0;
  const f16* asrc1;
  if (mat == 0) {
    asrc0 = xb + (size_t)(m0 + ar0) * HDIM;
    asrc1 = xb + (size_t)(m0 + ar1) * HDIM;
  } else {
    int g0 = (m0 + ar0 < kc) ? ridx[m0 + ar0] : 0;
    int g1 = (m0 + ar1 < kc) ? ridx[m0 + ar1] : 0;
    asrc0 = xb + (size_t)g0 * HDIM;
    asrc1 = xb + (size_t)g1 * HDIM;
  }
  const int slot = tid & 3;
  const int gs0 = slot ^ swz4(ar0);
  const int gs1 = slot ^ swz4(ar1);

  f32x16 acc[2][2] = {};

  for (int k0 = 0; k0 < HDIM; k0 += 32) {
    async_copy16((const char*)(asrc0 + k0) + gs0 * 16, (char*)lA + (wid * 64) * 16);
    async_copy16((const char*)(asrc1 + k0) + gs1 * 16, (char*)lA + (256 + wid * 64) * 16);
    async_copy16((const char*)(wbase + (size_t)(nb + ar0) * HDIM + k0) + gs0 * 16,
                 (char*)lB + (wid * 64) * 16);
    async_copy16((const char*)(wbase + (size_t)(nb + ar1) * HDIM + k0) + gs1 * 16,
                 (char*)lB + (256 + wid * 64) * 16);
    __syncthreads();
    #pragma unroll
    for (int kk = 0; kk < 2; ++kk) {
      f16x8 af[2], bf[2];
      #pragma unroll
      for (int mi = 0; mi < 2; ++mi) {
        int row = wm * 64 + mi * 32 + l31;
        af[mi] = *(const f16x8*)&lA[row * 32 + (((kk * 2 + hf) ^ swz4(row)) * 8)];
      }
      #pragma unroll
      for (int ni = 0; ni < 2; ++ni) {
        int row = wn * 64 + ni * 32 + l31;
        bf[ni] = *(const f16x8*)&lB[row * 32 + (((kk * 2 + hf) ^ swz4(row)) * 8)];
      }
      #pragma unroll
      for (int mi = 0; mi < 2; ++mi)
        #pragma unroll
        for (int ni = 0; ni < 2; ++ni)
          acc[mi][ni] = __builtin_amdgcn_mfma_f32_32x32x16_f16(af[mi], bf[ni], acc[mi][ni], 0, 0, 0);
    }
    __syncthreads();
  }

  const float* bias = (mat == 0) ? bq : (mat == 1) ? bk : bv;
  const float qscale = 0.125f * 1.44269504088896341f;  // 1/sqrt(64) * log2(e)
  f16* kvdst = (mat == 1) ? Kc : Vrow;
  #pragma unroll
  for (int mi = 0; mi < 2; ++mi) {
    #pragma unroll
    for (int ni = 0; ni < 2; ++ni) {
      int n = nb + wn * 64 + ni * 32 + l31;
      int head = n >> 6, d = n & 63;
      float b = bias[n];
      #pragma unroll
      for (int reg = 0; reg < 16; ++reg) {
        int s = m0 + wm * 64 + mi * 32 + (reg & 3) + 8 * (reg >> 2) + 4 * hf;
        float val = acc[mi][ni][reg] + b;
        if (mat == 0) {
          Qh[((size_t)head * S_LEN + s) * DHEAD + d] = (f16)(val * qscale);
        } else if (s < kc) {
          kvdst[((size_t)head * S_LEN + s) * DHEAD + d] = (f16)val;
        }
      }
    }
  }
}

// ---------------- V transpose [h][p][d] -> [h][d][rho] (key bits 2<->3 swapped) ----------
__global__ __launch_bounds__(256) void k_vt(const int* __restrict__ meta,
                                            const f16* __restrict__ Vrow,
                                            f16* __restrict__ Vtc,
                                            f16* __restrict__ Kc) {
  const int kc = meta[0];
  const int kcp = (kc + 63) & ~63;
  const int p0 = blockIdx.x * 64;
  const int h = blockIdx.y;
  const int tid = threadIdx.x;
  if (p0 >= kcp) return;
  if (p0 <= kc && kc < p0 + 64 && kc < kcp) {
    const int npad = kcp - kc;
    for (int u = tid; u < npad * 8; u += 256) {
      int r = kc + (u >> 3), c8 = u & 7;
      f16x8 z = {};
      *(f16x8*)&Kc[((size_t)h * S_LEN + r) * DHEAD + c8 * 8] = z;
    }
  }
  __shared__ __attribute__((aligned(16))) f16 lT[64 * 80];   // [d][p], stride 80
  for (int u = tid; u < 512; u += 256) {
    int d8 = u >> 6, p = u & 63;
    f16x8 v = {};
    if (p0 + p < kc) v = *(const f16x8*)&Vrow[((size_t)h * S_LEN + p0 + p) * DHEAD + d8 * 8];
    #pragma unroll
    for (int j = 0; j < 8; ++j) lT[(d8 * 8 + j) * 80 + p] = v[j];
  }
  __syncthreads();
  for (int w = tid; w < 512; w += 256) {
    int d = w >> 3, p8 = w & 7;
    int base16 = (p8 >> 1) * 16, half = p8 & 1;
    f16x4 lo = *(const f16x4*)&lT[d * 80 + base16 + half * 4];
    f16x4 hi = *(const f16x4*)&lT[d * 80 + base16 + 8 + half * 4];
    f16x8 o;
    o[0] = lo[0]; o[1] = lo[1]; o[2] = lo[2]; o[3] = lo[3];
    o[4] = hi[0]; o[5] = hi[1]; o[6] = hi[2]; o[7] = hi[3];
    *(f16x8*)&Vtc[((size_t)h * DHEAD + d) * S_LEN + p0 + p8 * 8] = o;
  }
}

// ---------------- flash attention: triple-buffered, counted-vmcnt pipeline (T3/T4-lite) --
// vs R3: stage TWO tiles ahead into a 3-deep LDS ring; replace __syncthreads (which
// drains vmcnt to 0 every tile -- the exposed-latency stall) with raw s_barrier +
// s_waitcnt vmcnt(4): each wave waits only for its tile-t loads (issued 2 iters ago),
// while t+1/t+2 stages stay in flight ACROSS the barrier. Zero extra VGPR state
// (the R5 spill failure mode is avoided: S/P registers identical to R3).
__global__ __launch_bounds__(256, 3) void k_attn(
    const f16* __restrict__ Qh, const f16* __restrict__ Kc, const f16* __restrict__ Vtc,
    const int* __restrict__ meta, f16* __restrict__ PO0, f16* __restrict__ PO1,
    float* __restrict__ PL) {
  __shared__ __attribute__((aligned(16))) f16 lK[3][64 * 64];   // [buf][key][d] swizzled
  __shared__ __attribute__((aligned(16))) f16 lV[3][64 * 64];   // [buf][d][rho] swizzled
  const int tid = threadIdx.x;
  const int wid = tid >> 6, lane = tid & 63;
  const int hf = lane >> 5, l31 = lane & 31, r7 = l31 & 7;

  // XCD head-clustering: 768 blocks, 96 contiguous work units per XCD (<=2 heads of K/V).
  const int lid = blockIdx.x;
  const int w = ((lid & 7) * 96) + (lid >> 3);
  const int head = w >> 6;
  const int rem = w & 63;
  const int split = rem >> 5;
  const int q0 = (rem & 31) * 128 + wid * 32;

  const int kc = meta[0];
  const int nkt = (kc + 63) >> 6;
  const int th = nkt >> 1;
  const int t0 = split ? th : 0;
  const int t1 = split ? nkt : th;

  // Q B-frags: lane n = q = l31, k = dc*16 + hf*8 + j  (held in regs whole kernel)
  const f16* Qp = Qh + ((size_t)head * S_LEN + q0 + l31) * DHEAD;
  f16x8 qf[4];
  #pragma unroll
  for (int dc = 0; dc < 4; ++dc) qf[dc] = *(const f16x8*)(Qp + dc * 16 + hf * 8);

  f32x16 accO[2] = {};     // [dh]: O columns dh*32+l31, rows = C-layout
  float ls0 = 0.f, ls1 = 0.f, ls2 = 0.f, ls3 = 0.f;

  const char* kbase = (const char*)(Kc + (size_t)head * S_LEN * DHEAD);
  const char* vbase = (const char*)(Vtc + (size_t)head * DHEAD * S_LEN);

  const int c0row = tid >> 3,         c0slot = tid & 7;
  const int c1row = (256 + tid) >> 3, c1slot = tid & 7;
  const int gs0 = c0slot ^ (c0row & 7);
  const int gs1 = c1slot ^ (c1row & 7);

  auto stage = [&](int t, int buf) {
    const int j0 = t * 64;
    async_copy16(kbase + (size_t)(j0 + c0row) * 128 + gs0 * 16,
                 (char*)&lK[buf][0] + (wid * 64) * 16);
    async_copy16(vbase + (size_t)c0row * (S_LEN * 2) + (size_t)j0 * 2 + gs0 * 16,
                 (char*)&lV[buf][0] + (wid * 64) * 16);
    async_copy16(kbase + (size_t)(j0 + c1row) * 128 + gs1 * 16,
                 (char*)&lK[buf][0] + (256 + wid * 64) * 16);
    async_copy16(vbase + (size_t)c1row * (S_LEN * 2) + (size_t)j0 * 2 + gs1 * 16,
                 (char*)&lV[buf][0] + (256 + wid * 64) * 16);
  };

  const int nt = t1 - t0;
  if (nt > 0) {
    stage(t0, 0);                            // 4 VMEM ops
    if (nt > 1) {
      stage(t0 + 1, 1);                      // 4 more in flight
      asm volatile("s_waitcnt vmcnt(4)" ::: "memory");   // tile t0 retired; t0+1 in flight
    } else {
      asm volatile("s_waitcnt vmcnt(0)" ::: "memory");
    }
    __builtin_amdgcn_sched_barrier(0);
    __builtin_amdgcn_s_barrier();            // all waves' tile-t0 LDS writes visible
    __builtin_amdgcn_sched_barrier(0);
  }

  int cur = 0;
  for (int t = t0; t < t1; ++t) {
    const bool more  = (t + 1 < t1);
    const bool have2 = (t + 2 < t1);
    const int nn = (cur >= 1) ? cur - 1 : cur + 2;   // (cur+2)%3 == buffer of tile t+2
    if (have2) stage(t + 2, nn);             // issue 2-ahead; stays in flight over barrier

    #pragma unroll
    for (int mh = 0; mh < 2; ++mh) {
      f16x8 af[4];
      const int arow = mh * 32 + l31;
      #pragma unroll
      for (int dc = 0; dc < 4; ++dc)
        af[dc] = *(const f16x8*)&lK[cur][arow * 64 + ((((dc << 1) | hf) ^ r7) * 8)];
      f32x16 s = {};
      #pragma unroll
      for (int dc = 0; dc < 4; ++dc)
        s = __builtin_amdgcn_mfma_f32_32x32x16_f16(af[dc], qf[dc], s, 0, 0, 0);
      #pragma unroll
      for (int u = 0; u < 16; ++u) {
        s[u] = fast_exp2(s[u]);
        if ((u & 3) == 0) ls0 += s[u];
        else if ((u & 3) == 1) ls1 += s[u];
        else if ((u & 3) == 2) ls2 += s[u];
        else ls3 += s[u];
      }
      #pragma unroll
      for (int cc = 0; cc < 2; ++cc) {
        f16x8 pf;
        #pragma unroll
        for (int u = 0; u < 8; ++u) pf[u] = (f16)s[8 * cc + u];
        const int c2 = mh * 2 + cc;
        #pragma unroll
        for (int dh = 0; dh < 2; ++dh) {
          const int vrow = dh * 32 + l31;
          f16x8 vf = *(const f16x8*)&lV[cur][vrow * 64 + ((((c2 << 1) | hf) ^ r7) * 8)];
          accO[dh] = __builtin_amdgcn_mfma_f32_32x32x16_f16(pf, vf, accO[dh], 0, 0, 0);
        }
      }
    }

    if (more) {
      // wait for tile t+1 (issued 1-2 iters ago); keep t+2's 4 loads in flight
      if (have2) asm volatile("s_waitcnt vmcnt(4)" ::: "memory");
      else       asm volatile("s_waitcnt vmcnt(0)" ::: "memory");
      __builtin_amdgcn_sched_barrier(0);
      __builtin_amdgcn_s_barrier();          // tile t reads done block-wide; t+1 published
      __builtin_amdgcn_sched_barrier(0);
    }
    cur = (cur == 2) ? 0 : cur + 1;
  }

  float lsum = (ls0 + ls1) + (ls2 + ls3);
  lsum += __shfl_xor(lsum, 32);
  if (split == 1) lsum -= (float)(nkt * 64 - kc);
  if (hf == 0)
    PL[((size_t)split * NHEAD + head) * S_LEN + q0 + l31] = lsum;

  // coalesced PO store via LDS bounce (reuse dead lK region)
  __syncthreads();
  f16* ost = (f16*)lK;
  #pragma unroll
  for (int dh = 0; dh < 2; ++dh)
    #pragma unroll
    for (int reg = 0; reg < 16; ++reg) {
      int row = (reg & 3) + 8 * (reg >> 2) + 4 * hf;
      ost[wid * 2048 + row * 64 + dh * 32 + l31] = (f16)accO[dh][reg];
    }
  f16* PO = split ? PO1 : PO0;
  const f16* osrc = ost + wid * 2048;
  #pragma unroll
  for (int p = 0; p < 4; ++p) {
    int row = p * 8 + (lane >> 3), sl = lane & 7;
    f16x8 v = *(const f16x8*)&osrc[row * 64 + sl * 8];
    *(f16x8*)&PO[((size_t)head * S_LEN + q0 + row) * DHEAD + sl * 8] = v;
  }
}

// ---------------- output projection GEMM: 128x64 tiles, BK=64, 384 blocks, XCD-grouped ---
__global__ __launch_bounds__(256) void k_out(
    const f16* __restrict__ PO0, const f16* __restrict__ PO1,
    const float* __restrict__ PL, const f16* __restrict__ wo,
    const float* __restrict__ bo, float* __restrict__ out) {
  __shared__ __attribute__((aligned(16))) f16 lA[128 * 64];   // 16KB
  __shared__ __attribute__((aligned(16))) f16 lB[64 * 64];    // 8KB
  __shared__ float linv[NHEAD * 128];
  const int tid = threadIdx.x;
  const int wid = tid >> 6, lane = tid & 63;
  const int hf = lane >> 5, l31 = lane & 31;
  const int wm = wid >> 1, wn = wid & 1;     // 2x2 waves of 64m x 32n
  const int lid = blockIdx.x;
  const int w = ((lid & 7) * 48) + (lid >> 3);   // XCD-grouped: 48 units/XCD share m-tiles
  const int nb = (w % 12) * 64;
  const int m0 = (w / 12) * 128;

  for (int i = tid; i < NHEAD * 128; i += 256) {
    int h = i >> 7, r = i & 127;
    float l = PL[(size_t)h * S_LEN + m0 + r] + PL[(size_t)(NHEAD + h) * S_LEN + m0 + r];
    linv[i] = 1.0f / l;
  }
  __syncthreads();

  f32x16 acc[2] = {};   // [mi]

  for (int head = 0; head < NHEAD; ++head) {   // BK=64 == one head per step
    #pragma unroll
    for (int it = 0; it < 4; ++it) {
      int c = it * 256 + tid;
      int row = c >> 3, slot = c & 7;
      int gs = slot ^ (row & 7);
      size_t pi = ((size_t)head * S_LEN + m0 + row) * DHEAD + gs * 8;
      f16x8 a0 = *(const f16x8*)(PO0 + pi);
      f16x8 a1 = *(const f16x8*)(PO1 + pi);
      float il = linv[head * 128 + row];
      f16x8 av;
      #pragma unroll
      for (int u = 0; u < 8; ++u) av[u] = (f16)(((float)a0[u] + (float)a1[u]) * il);
      *(f16x8*)&lA[c * 8] = av;
    }
    #pragma unroll
    for (int it = 0; it < 2; ++it) {
      int c = it * 256 + tid;
      int row = c >> 3, slot = c & 7;
      int gs = slot ^ (row & 7);
      async_copy16((const char*)(wo + (size_t)(nb + row) * HDIM + head * 64) + gs * 16,
                   (char*)lB + (it * 256 + wid * 64) * 16);
    }
    __syncthreads();
    #pragma unroll
    for (int kk = 0; kk < 4; ++kk) {
      f16x8 af[2], bf;
      #pragma unroll
      for (int mi = 0; mi < 2; ++mi) {
        int row = wm * 64 + mi * 32 + l31;
        af[mi] = *(const f16x8*)&lA[row * 64 + ((((kk << 1) | hf) ^ (row & 7)) * 8)];
      }
      int rb = wn * 32 + l31;
      bf = *(const f16x8*)&lB[rb * 64 + ((((kk << 1) | hf) ^ (rb & 7)) * 8)];
      #pragma unroll
      for (int mi = 0; mi < 2; ++mi)
        acc[mi] = __builtin_amdgcn_mfma_f32_32x32x16_f16(af[mi], bf, acc[mi], 0, 0, 0);
    }
    __syncthreads();
  }

  const int n = nb + wn * 32 + l31;
  const float b = bo[n];
  #pragma unroll
  for (int mi = 0; mi < 2; ++mi) {
    #pragma unroll
    for (int reg = 0; reg < 16; ++reg) {
      int s = m0 + wm * 64 + mi * 32 + (reg & 3) + 8 * (reg >> 2) + 4 * hf;
      out[(size_t)s * HDIM + n] = acc[mi][reg] + b;
    }
  }
}

extern "C" void kernel_launch(void* const* d_in, const int* in_sizes, int n_in,
                              void* d_out, int out_size, void* d_ws, size_t ws_size,
                              hipStream_t stream) {
  const float* x  = (const float*)d_in[0];
  const float* Wq = (const float*)d_in[1];
  const float* bq = (const float*)d_in[2];
  const float* Wk = (const float*)d_in[3];
  const float* bk = (const float*)d_in[4];
  const float* Wv = (const float*)d_in[5];
  const float* bv = (const float*)d_in[6];
  const float* Wo = (const float*)d_in[7];
  const float* bo = (const float*)d_in[8];
  const int*   mask = (const int*)d_in[9];
  float* out = (float*)d_out;

  char* ws = (char*)d_ws;
  int* meta  = (int*)(ws + OFF_META);
  int* ridx  = (int*)(ws + OFF_RIDX);
  f16* xb    = (f16*)(ws + OFF_XB);
  f16* wqkv  = (f16*)(ws + OFF_WQKV);
  f16* wob   = (f16*)(ws + OFF_WO);
  f16* Qh    = (f16*)(ws + OFF_Q);
  f16* Kc    = (f16*)(ws + OFF_K);
  f16* Vtc   = (f16*)(ws + OFF_VT);
  f16* Vrow  = (f16*)(ws + OFF_VR);
  f16* PO0   = (f16*)(ws + OFF_VR);     // reuses Vrow after k_vt
  f16* PO1   = (f16*)(ws + OFF_PO1);
  float* PL  = (float*)(ws + OFF_WQKV); // reuses wqkv after k_qkv

  k_prep<<<dim3(5377), 256, 0, stream>>>(x, Wq, Wk, Wv, Wo, mask, xb, ridx, meta);
  k_qkv<<<dim3(18, 32), 256, 0, stream>>>(xb, wqkv, bq, bk, bv, ridx, meta, Qh, Kc, Vrow);
  k_vt<<<dim3(64, NHEAD), 256, 0, stream>>>(meta, Vrow, Vtc, Kc);
  k_attn<<<dim3(768), 256, 0, stream>>>(Qh, Kc, Vtc, meta, PO0, PO1, PL);
  k_out<<<dim3(384), 256, 0, stream>>>(PO0, PO1, PL, wob, bo, out);
}

// Round 8
// 177.166 us; speedup vs baseline: 1.0071x; 1.0071x over previous
//
#include <hip/hip_runtime.h>
#include <stdint.h>

#define S_LEN 4096
#define HDIM  768
#define NHEAD 12
#define DHEAD 64

typedef _Float16 f16;
typedef __attribute__((ext_vector_type(8)))  _Float16 f16x8;
typedef __attribute__((ext_vector_type(4)))  _Float16 f16x4;
typedef __attribute__((ext_vector_type(4)))  float    f32x4;
typedef __attribute__((ext_vector_type(16))) float    f32x16;

typedef __attribute__((address_space(1))) void gv_t;
typedef __attribute__((address_space(3))) void lv_t;

__device__ __forceinline__ void async_copy16(const void* g, void* l) {
  __builtin_amdgcn_global_load_lds((gv_t*)g, (lv_t*)l, 16, 0, 0);
}

__device__ __forceinline__ float fast_exp2(float x) {
#if __has_builtin(__builtin_amdgcn_exp2f)
  return __builtin_amdgcn_exp2f(x);
#else
  return exp2f(x);
#endif
}

__device__ __forceinline__ int swz4(int row) { return (row ^ (row >> 2)) & 3; }

// ---------------- workspace layout (heavy reuse) ----------------
constexpr size_t OFF_META = 0;                          // int kcount
constexpr size_t OFF_RIDX = 256;                        // int[4096] inverse map p->s
constexpr size_t OFF_XB   = 65536;                      // f16 x[4096*768]
constexpr size_t SZ_XB    = (size_t)S_LEN * HDIM * 2;
constexpr size_t OFF_WQKV = OFF_XB + SZ_XB;             // f16[3*768*768]; later PL
constexpr size_t SZ_WQKV  = (size_t)3 * HDIM * HDIM * 2;
constexpr size_t OFF_WO   = OFF_WQKV + SZ_WQKV;         // f16[768*768]
constexpr size_t SZ_WO    = (size_t)HDIM * HDIM * 2;
constexpr size_t OFF_Q    = OFF_WO + SZ_WO;             // f16[12][4096][64]
constexpr size_t SZ_HD    = (size_t)NHEAD * S_LEN * DHEAD * 2;
constexpr size_t OFF_K    = OFF_Q + SZ_HD;              // f16[12][4096][64] compacted
constexpr size_t OFF_VT   = OFF_K + SZ_HD;              // f16[12][64][4096] transposed+permuted V
constexpr size_t OFF_VR   = OFF_VT + SZ_HD;             // f16[12][4096][64] V rows; later PO split0
constexpr size_t OFF_PO1  = OFF_VR + SZ_HD;             // f16[12][4096][64] PO split1

// ---------------- prep: fp32->fp16 convert + mask compaction (inverse map) ----------------
__global__ __launch_bounds__(256) void k_prep(const float* __restrict__ x,
                                              const float* __restrict__ wq,
                                              const float* __restrict__ wk,
                                              const float* __restrict__ wv,
                                              const float* __restrict__ wo,
                                              const int* __restrict__ mi,
                                              f16* __restrict__ dst,
                                              int* __restrict__ ridx,
                                              int* __restrict__ meta) {
  __shared__ int s_flag;
  __shared__ int s_cnt[256];
  const int b = blockIdx.x, tid = threadIdx.x;
  if (b < 5376) {
    int i = b * 256 + tid;                   // 1376256 float4 units
    const float* src; int off;
    if (i < 786432) { src = x; off = i; }
    else {
      int j = i - 786432;
      int w = j / 147456;
      off = j - w * 147456;
      src = (w == 0) ? wq : (w == 1) ? wk : (w == 2) ? wv : wo;
    }
    float4 v = ((const float4*)src)[off];
    f16x4 h;
    h[0] = (f16)v.x; h[1] = (f16)v.y; h[2] = (f16)v.z; h[3] = (f16)v.w;
    ((f16x4*)dst)[i] = h;
    return;
  }
  // ---- mask block ----
  if (tid == 0) s_flag = 1;
  __syncthreads();
  int bad = 0;
  #pragma unroll
  for (int k = 0; k < 4; ++k) {
    int v = mi[k * 256 + tid];
    if (v != 0 && v != 1) bad = 1;
  }
  if (bad) atomicAnd(&s_flag, 0);
  __syncthreads();
  const int isInt = s_flag;
  const unsigned char* mu8 = (const unsigned char*)mi;
  int keep[16]; int cnt = 0;
  const int s0 = tid * 16;
  #pragma unroll
  for (int k = 0; k < 16; ++k) {
    int mval = isInt ? mi[s0 + k] : (int)mu8[s0 + k];
    keep[k] = (mval == 0) ? 1 : 0;           // True => masked out (excluded)
    cnt += keep[k];
    ridx[s0 + k] = 0;                        // zero-fill inverse map (pad-safe)
  }
  s_cnt[tid] = cnt;
  __syncthreads();
  for (int off = 1; off < 256; off <<= 1) {
    int t = (tid >= off) ? s_cnt[tid - off] : 0;
    __syncthreads();
    s_cnt[tid] += t;
    __syncthreads();
  }
  int base = s_cnt[tid] - cnt;               // exclusive prefix
  #pragma unroll
  for (int k = 0; k < 16; ++k) {
    if (keep[k]) { ridx[base] = s0 + k; ++base; }
  }
  if (tid == 255) meta[0] = s_cnt[255];
}

// ---------------- fused QKV projection GEMM (32x32x16 MFMA, compacted K/V rows) ---------
__global__ __launch_bounds__(256) void k_qkv(
    const f16* __restrict__ xb, const f16* __restrict__ wqkv,
    const float* __restrict__ bq, const float* __restrict__ bk, const float* __restrict__ bv,
    const int* __restrict__ ridx, const int* __restrict__ meta,
    f16* __restrict__ Qh, f16* __restrict__ Kc, f16* __restrict__ Vrow) {
  __shared__ __attribute__((aligned(16))) f16 lA[128 * 32];
  __shared__ __attribute__((aligned(16))) f16 lB[128 * 32];
  const int tid = threadIdx.x;
  const int wid = tid >> 6, lane = tid & 63;
  const int hf = lane >> 5, l31 = lane & 31;
  const int wm = wid >> 1, wn = wid & 1;
  const int tn = blockIdx.x;
  const int m0 = blockIdx.y * 128;
  const int mat = tn / 6;
  const int nb = (tn % 6) * 128;
  const int kc = meta[0];
  if (mat != 0 && m0 >= kc) return;          // fully-pad K/V tile
  const f16* wbase = wqkv + (size_t)mat * HDIM * HDIM;

  const int ar0 = tid >> 2, ar1 = 64 + (tid >> 2);
  const f16* asrc0;
  const f16* asrc1;
  if (mat == 0) {
    asrc0 = xb + (size_t)(m0 + ar0) * HDIM;
    asrc1 = xb + (size_t)(m0 + ar1) * HDIM;
  } else {
    int g0 = (m0 + ar0 < kc) ? ridx[m0 + ar0] : 0;
    int g1 = (m0 + ar1 < kc) ? ridx[m0 + ar1] : 0;
    asrc0 = xb + (size_t)g0 * HDIM;
    asrc1 = xb + (size_t)g1 * HDIM;
  }
  const int slot = tid & 3;
  const int gs0 = slot ^ swz4(ar0);
  const int gs1 = slot ^ swz4(ar1);

  f32x16 acc[2][2] = {};

  for (int k0 = 0; k0 < HDIM; k0 += 32) {
    async_copy16((const char*)(asrc0 + k0) + gs0 * 16, (char*)lA + (wid * 64) * 16);
    async_copy16((const char*)(asrc1 + k0) + gs1 * 16, (char*)lA + (256 + wid * 64) * 16);
    async_copy16((const char*)(wbase + (size_t)(nb + ar0) * HDIM + k0) + gs0 * 16,
                 (char*)lB + (wid * 64) * 16);
    async_copy16((const char*)(wbase + (size_t)(nb + ar1) * HDIM + k0) + gs1 * 16,
                 (char*)lB + (256 + wid * 64) * 16);
    __syncthreads();
    #pragma unroll
    for (int kk = 0; kk < 2; ++kk) {
      f16x8 af[2], bf[2];
      #pragma unroll
      for (int mi = 0; mi < 2; ++mi) {
        int row = wm * 64 + mi * 32 + l31;
        af[mi] = *(const f16x8*)&lA[row * 32 + (((kk * 2 + hf) ^ swz4(row)) * 8)];
      }
      #pragma unroll
      for (int ni = 0; ni < 2; ++ni) {
        int row = wn * 64 + ni * 32 + l31;
        bf[ni] = *(const f16x8*)&lB[row * 32 + (((kk * 2 + hf) ^ swz4(row)) * 8)];
      }
      #pragma unroll
      for (int mi = 0; mi < 2; ++mi)
        #pragma unroll
        for (int ni = 0; ni < 2; ++ni)
          acc[mi][ni] = __builtin_amdgcn_mfma_f32_32x32x16_f16(af[mi], bf[ni], acc[mi][ni], 0, 0, 0);
    }
    __syncthreads();
  }

  const float* bias = (mat == 0) ? bq : (mat == 1) ? bk : bv;
  const float qscale = 0.125f * 1.44269504088896341f;  // 1/sqrt(64) * log2(e)
  f16* kvdst = (mat == 1) ? Kc : Vrow;
  #pragma unroll
  for (int mi = 0; mi < 2; ++mi) {
    #pragma unroll
    for (int ni = 0; ni < 2; ++ni) {
      int n = nb + wn * 64 + ni * 32 + l31;
      int head = n >> 6, d = n & 63;
      float b = bias[n];
      #pragma unroll
      for (int reg = 0; reg < 16; ++reg) {
        int s = m0 + wm * 64 + mi * 32 + (reg & 3) + 8 * (reg >> 2) + 4 * hf;
        float val = acc[mi][ni][reg] + b;
        if (mat == 0) {
          Qh[((size_t)head * S_LEN + s) * DHEAD + d] = (f16)(val * qscale);
        } else if (s < kc) {
          kvdst[((size_t)head * S_LEN + s) * DHEAD + d] = (f16)val;
        }
      }
    }
  }
}

// ---------------- V transpose [h][p][d] -> [h][d][rho] (key bits 2<->3 swapped) ----------
__global__ __launch_bounds__(256) void k_vt(const int* __restrict__ meta,
                                            const f16* __restrict__ Vrow,
                                            f16* __restrict__ Vtc,
                                            f16* __restrict__ Kc) {
  const int kc = meta[0];
  const int kcp = (kc + 63) & ~63;
  const int p0 = blockIdx.x * 64;
  const int h = blockIdx.y;
  const int tid = threadIdx.x;
  if (p0 >= kcp) return;
  if (p0 <= kc && kc < p0 + 64 && kc < kcp) {
    const int npad = kcp - kc;
    for (int u = tid; u < npad * 8; u += 256) {
      int r = kc + (u >> 3), c8 = u & 7;
      f16x8 z = {};
      *(f16x8*)&Kc[((size_t)h * S_LEN + r) * DHEAD + c8 * 8] = z;
    }
  }
  __shared__ __attribute__((aligned(16))) f16 lT[64 * 80];   // [d][p], stride 80
  for (int u = tid; u < 512; u += 256) {
    int d8 = u >> 6, p = u & 63;
    f16x8 v = {};
    if (p0 + p < kc) v = *(const f16x8*)&Vrow[((size_t)h * S_LEN + p0 + p) * DHEAD + d8 * 8];
    #pragma unroll
    for (int j = 0; j < 8; ++j) lT[(d8 * 8 + j) * 80 + p] = v[j];
  }
  __syncthreads();
  for (int w = tid; w < 512; w += 256) {
    int d = w >> 3, p8 = w & 7;
    int base16 = (p8 >> 1) * 16, half = p8 & 1;
    f16x4 lo = *(const f16x4*)&lT[d * 80 + base16 + half * 4];
    f16x4 hi = *(const f16x4*)&lT[d * 80 + base16 + 8 + half * 4];
    f16x8 o;
    o[0] = lo[0]; o[1] = lo[1]; o[2] = lo[2]; o[3] = lo[3];
    o[4] = hi[0]; o[5] = hi[1]; o[6] = hi[2]; o[7] = hi[3];
    *(f16x8*)&Vtc[((size_t)h * DHEAD + d) * S_LEN + p0 + p8 * 8] = o;
  }
}

// ---------------- flash attention: 64q/wave (halved LDS reads/FLOP), 2-split -------------
// Arithmetic (R2/R5 counters): every wave reads the FULL 16KB K/V tile per iteration;
// per CU the LDS read port demand (~2700cyc/window) exceeds the window (~2020cyc) -- LDS
// port is the saturated pipe, which is why MfmaUtil/VALUBusy/occupancy all sit low and
// why pipelining attempts (R5/R7) were neutral. 64q/wave makes each af/vf fragment feed
// 2 MFMAs: total attn LDS reads halve. R2's bundled regressions are NOT repeated here:
// 2-split kept (no extra Q/PO traffic), coalesced LDS-bounce stores kept (no write amp),
// launch_bounds(256,2) gives the allocator slack (anti-spill).
__global__ __launch_bounds__(256, 2) void k_attn(
    const f16* __restrict__ Qh, const f16* __restrict__ Kc, const f16* __restrict__ Vtc,
    const int* __restrict__ meta, f16* __restrict__ PO0, f16* __restrict__ PO1,
    float* __restrict__ PL) {
  // single pool: [0..1]=K bufs, [2..3]=V bufs; whole 32KB reused as O-bounce at the end
  __shared__ __attribute__((aligned(16))) f16 lKV[4][64 * 64];
  const int tid = threadIdx.x;
  const int wid = tid >> 6, lane = tid & 63;
  const int hf = lane >> 5, l31 = lane & 31, r7 = l31 & 7;

  // XCD clustering: 384 blocks, 48 contiguous work units per XCD (1.5 heads of K/V each).
  const int lid = blockIdx.x;
  const int w = ((lid & 7) * 48) + (lid >> 3);
  const int head = w >> 5;
  const int rem = w & 31;               // 2 splits x 16 q-blocks
  const int split = rem >> 4;
  const int qw = (rem & 15) * 256 + wid * 64;   // wave's 64-query base

  const int kc = meta[0];
  const int nkt = (kc + 63) >> 6;
  const int th = nkt >> 1;
  const int t0 = split ? th : 0;
  const int t1 = split ? nkt : th;

  // Q B-frags for both 32q halves: lane n = q = l31, k = dc*16 + hf*8 + j
  f16x8 qf[2][4];
  #pragma unroll
  for (int qb = 0; qb < 2; ++qb) {
    const f16* Qp = Qh + ((size_t)head * S_LEN + qw + qb * 32 + l31) * DHEAD;
    #pragma unroll
    for (int dc = 0; dc < 4; ++dc) qf[qb][dc] = *(const f16x8*)(Qp + dc * 16 + hf * 8);
  }

  f32x16 accO[2][2] = {};   // [qb][dh]
  float ls[2][2] = {};      // [qb][parity]

  const char* kbase = (const char*)(Kc + (size_t)head * S_LEN * DHEAD);
  const char* vbase = (const char*)(Vtc + (size_t)head * DHEAD * S_LEN);

  const int c0row = tid >> 3,         c0slot = tid & 7;
  const int c1row = (256 + tid) >> 3, c1slot = tid & 7;
  const int gs0 = c0slot ^ (c0row & 7);
  const int gs1 = c1slot ^ (c1row & 7);

  auto stage = [&](int t, int buf) {
    const int j0 = t * 64;
    async_copy16(kbase + (size_t)(j0 + c0row) * 128 + gs0 * 16,
                 (char*)&lKV[buf][0] + (wid * 64) * 16);
    async_copy16(vbase + (size_t)c0row * (S_LEN * 2) + (size_t)j0 * 2 + gs0 * 16,
                 (char*)&lKV[2 + buf][0] + (wid * 64) * 16);
    async_copy16(kbase + (size_t)(j0 + c1row) * 128 + gs1 * 16,
                 (char*)&lKV[buf][0] + (256 + wid * 64) * 16);
    async_copy16(vbase + (size_t)c1row * (S_LEN * 2) + (size_t)j0 * 2 + gs1 * 16,
                 (char*)&lKV[2 + buf][0] + (256 + wid * 64) * 16);
  };

  int cur = 0;
  if (t0 < t1) {
    stage(t0, 0);
    __syncthreads();
  }

  for (int t = t0; t < t1; ++t) {
    const bool more = (t + 1 < t1);
    if (more) stage(t + 1, cur ^ 1);

    #pragma unroll
    for (int mh = 0; mh < 2; ++mh) {
      // K A-frags: lane m = key = mh*32 + l31 (shared by both qb halves)
      f16x8 af[4];
      const int arow = mh * 32 + l31;
      #pragma unroll
      for (int dc = 0; dc < 4; ++dc)
        af[dc] = *(const f16x8*)&lKV[cur][arow * 64 + ((((dc << 1) | hf) ^ r7) * 8)];

      f16x8 pf[2][2];   // [qb][cc]
      #pragma unroll
      for (int qb = 0; qb < 2; ++qb) {
        f32x16 s = {};
        #pragma unroll
        for (int dc = 0; dc < 4; ++dc)
          s = __builtin_amdgcn_mfma_f32_32x32x16_f16(af[dc], qf[qb][dc], s, 0, 0, 0);
        #pragma unroll
        for (int u = 0; u < 16; ++u) {
          s[u] = fast_exp2(s[u]);
          ls[qb][u & 1] += s[u];
        }
        #pragma unroll
        for (int cc = 0; cc < 2; ++cc)
          #pragma unroll
          for (int u = 0; u < 8; ++u) pf[qb][cc][u] = (f16)s[8 * cc + u];
      }
      // PV: each vf fragment feeds both qb accumulators
      #pragma unroll
      for (int cc = 0; cc < 2; ++cc) {
        const int c2 = mh * 2 + cc;
        #pragma unroll
        for (int dh = 0; dh < 2; ++dh) {
          const int vrow = dh * 32 + l31;
          f16x8 vf = *(const f16x8*)&lKV[2 + cur][vrow * 64 + ((((c2 << 1) | hf) ^ r7) * 8)];
          accO[0][dh] = __builtin_amdgcn_mfma_f32_32x32x16_f16(pf[0][cc], vf, accO[0][dh], 0, 0, 0);
          accO[1][dh] = __builtin_amdgcn_mfma_f32_32x32x16_f16(pf[1][cc], vf, accO[1][dh], 0, 0, 0);
        }
      }
    }

    if (more) {
      __syncthreads();
      cur ^= 1;
    }
  }

  f16* PO = split ? PO1 : PO0;
  // coalesced PO store: bounce wave's 64x64 f16 O-tile through LDS (8KB/wave, 32KB pool)
  __syncthreads();                       // all waves done reading lKV
  f16* ost = (f16*)lKV + wid * 4096;
  #pragma unroll
  for (int qb = 0; qb < 2; ++qb) {
    float lsum = ls[qb][0] + ls[qb][1];
    lsum += __shfl_xor(lsum, 32);           // fold hf halves
    if (split == 1) lsum -= (float)(nkt * 64 - kc);   // pad tile lives in split 1
    if (hf == 0)
      PL[((size_t)split * NHEAD + head) * S_LEN + qw + qb * 32 + l31] = lsum;
    #pragma unroll
    for (int dh = 0; dh < 2; ++dh)
      #pragma unroll
      for (int reg = 0; reg < 16; ++reg) {
        int row = qb * 32 + (reg & 3) + 8 * (reg >> 2) + 4 * hf;
        ost[row * 64 + dh * 32 + l31] = (f16)accO[qb][dh][reg];
      }
  }
  #pragma unroll
  for (int p = 0; p < 8; ++p) {
    int row = p * 8 + (lane >> 3), sl = lane & 7;
    f16x8 v = *(const f16x8*)&ost[row * 64 + sl * 8];
    *(f16x8*)&PO[((size_t)head * S_LEN + qw + row) * DHEAD + sl * 8] = v;
  }
}

// ---------------- output projection GEMM: 128x64 tiles, BK=64, 384 blocks, XCD-grouped ---
__global__ __launch_bounds__(256) void k_out(
    const f16* __restrict__ PO0, const f16* __restrict__ PO1,
    const float* __restrict__ PL, const f16* __restrict__ wo,
    const float* __restrict__ bo, float* __restrict__ out) {
  __shared__ __attribute__((aligned(16))) f16 lA[128 * 64];   // 16KB
  __shared__ __attribute__((aligned(16))) f16 lB[64 * 64];    // 8KB
  __shared__ float linv[NHEAD * 128];
  const int tid = threadIdx.x;
  const int wid = tid >> 6, lane = tid & 63;
  const int hf = lane >> 5, l31 = lane & 31;
  const int wm = wid >> 1, wn = wid & 1;     // 2x2 waves of 64m x 32n
  const int lid = blockIdx.x;
  const int w = ((lid & 7) * 48) + (lid >> 3);   // XCD-grouped: 48 units/XCD share m-tiles
  const int nb = (w % 12) * 64;
  const int m0 = (w / 12) * 128;

  for (int i = tid; i < NHEAD * 128; i += 256) {
    int h = i >> 7, r = i & 127;
    float l = PL[(size_t)h * S_LEN + m0 + r] + PL[(size_t)(NHEAD + h) * S_LEN + m0 + r];
    linv[i] = 1.0f / l;
  }
  __syncthreads();

  f32x16 acc[2] = {};   // [mi]

  for (int head = 0; head < NHEAD; ++head) {   // BK=64 == one head per step
    #pragma unroll
    for (int it = 0; it < 4; ++it) {
      int c = it * 256 + tid;
      int row = c >> 3, slot = c & 7;
      int gs = slot ^ (row & 7);
      size_t pi = ((size_t)head * S_LEN + m0 + row) * DHEAD + gs * 8;
      f16x8 a0 = *(const f16x8*)(PO0 + pi);
      f16x8 a1 = *(const f16x8*)(PO1 + pi);
      float il = linv[head * 128 + row];
      f16x8 av;
      #pragma unroll
      for (int u = 0; u < 8; ++u) av[u] = (f16)(((float)a0[u] + (float)a1[u]) * il);
      *(f16x8*)&lA[c * 8] = av;
    }
    #pragma unroll
    for (int it = 0; it < 2; ++it) {
      int c = it * 256 + tid;
      int row = c >> 3, slot = c & 7;
      int gs = slot ^ (row & 7);
      async_copy16((const char*)(wo + (size_t)(nb + row) * HDIM + head * 64) + gs * 16,
                   (char*)lB + (it * 256 + wid * 64) * 16);
    }
    __syncthreads();
    #pragma unroll
    for (int kk = 0; kk < 4; ++kk) {
      f16x8 af[2], bf;
      #pragma unroll
      for (int mi = 0; mi < 2; ++mi) {
        int row = wm * 64 + mi * 32 + l31;
        af[mi] = *(const f16x8*)&lA[row * 64 + ((((kk << 1) | hf) ^ (row & 7)) * 8)];
      }
      int rb = wn * 32 + l31;
      bf = *(const f16x8*)&lB[rb * 64 + ((((kk << 1) | hf) ^ (rb & 7)) * 8)];
      #pragma unroll
      for (int mi = 0; mi < 2; ++mi)
        acc[mi] = __builtin_amdgcn_mfma_f32_32x32x16_f16(af[mi], bf, acc[mi], 0, 0, 0);
    }
    __syncthreads();
  }

  const int n = nb + wn * 32 + l31;
  const float b = bo[n];
  #pragma unroll
  for (int mi = 0; mi < 2; ++mi) {
    #pragma unroll
    for (int reg = 0; reg < 16; ++reg) {
      int s = m0 + wm * 64 + mi * 32 + (reg & 3) + 8 * (reg >> 2) + 4 * hf;
      out[(size_t)s * HDIM + n] = acc[mi][reg] + b;
    }
  }
}

extern "C" void kernel_launch(void* const* d_in, const int* in_sizes, int n_in,
                              void* d_out, int out_size, void* d_ws, size_t ws_size,
                              hipStream_t stream) {
  const float* x  = (const float*)d_in[0];
  const float* Wq = (const float*)d_in[1];
  const float* bq = (const float*)d_in[2];
  const float* Wk = (const float*)d_in[3];
  const float* bk = (const float*)d_in[4];
  const float* Wv = (const float*)d_in[5];
  const float* bv = (const float*)d_in[6];
  const float* Wo = (const float*)d_in[7];
  const float* bo = (const float*)d_in[8];
  const int*   mask = (const int*)d_in[9];
  float* out = (float*)d_out;

  char* ws = (char*)d_ws;
  int* meta  = (int*)(ws + OFF_META);
  int* ridx  = (int*)(ws + OFF_RIDX);
  f16* xb    = (f16*)(ws + OFF_XB);
  f16* wqkv  = (f16*)(ws + OFF_WQKV);
  f16* wob   = (f16*)(ws + OFF_WO);
  f16* Qh    = (f16*)(ws + OFF_Q);
  f16* Kc    = (f16*)(ws + OFF_K);
  f16* Vtc   = (f16*)(ws + OFF_VT);
  f16* Vrow  = (f16*)(ws + OFF_VR);
  f16* PO0   = (f16*)(ws + OFF_VR);     // reuses Vrow after k_vt
  f16* PO1   = (f16*)(ws + OFF_PO1);
  float* PL  = (float*)(ws + OFF_WQKV); // reuses wqkv after k_qkv

  k_prep<<<dim3(5377), 256, 0, stream>>>(x, Wq, Wk, Wv, Wo, mask, xb, ridx, meta);
  k_qkv<<<dim3(18, 32), 256, 0, stream>>>(xb, wqkv, bq, bk, bv, ridx, meta, Qh, Kc, Vrow);
  k_vt<<<dim3(64, NHEAD), 256, 0, stream>>>(meta, Vrow, Vtc, Kc);
  k_attn<<<dim3(384), 256, 0, stream>>>(Qh, Kc, Vtc, meta, PO0, PO1, PL);
  k_out<<<dim3(384), 256, 0, stream>>>(PO0, PO1, PL, wob, bo, out);
}

// Round 9
// 170.932 us; speedup vs baseline: 1.0438x; 1.0365x over previous
//
#include <hip/hip_runtime.h>
#include <stdint.h>

#define S_LEN 4096
#define HDIM  768
#define NHEAD 12
#define DHEAD 64

typedef _Float16 f16;
typedef __attribute__((ext_vector_type(8)))  _Float16 f16x8;
typedef __attribute__((ext_vector_type(4)))  _Float16 f16x4;
typedef __attribute__((ext_vector_type(4)))  float    f32x4;
typedef __attribute__((ext_vector_type(16))) float    f32x16;

typedef __attribute__((address_space(1))) void gv_t;
typedef __attribute__((address_space(3))) void lv_t;

__device__ __forceinline__ void async_copy16(const void* g, void* l) {
  __builtin_amdgcn_global_load_lds((gv_t*)g, (lv_t*)l, 16, 0, 0);
}

__device__ __forceinline__ float fast_exp2(float x) {
#if __has_builtin(__builtin_amdgcn_exp2f)
  return __builtin_amdgcn_exp2f(x);
#else
  return exp2f(x);
#endif
}

__device__ __forceinline__ int swz4(int row) { return (row ^ (row >> 2)) & 3; }

// ---------------- workspace layout (heavy reuse) ----------------
constexpr size_t OFF_META = 0;                          // int kcount
constexpr size_t OFF_RIDX = 256;                        // int[4096] inverse map p->s
constexpr size_t OFF_XB   = 65536;                      // f16 x[4096*768]
constexpr size_t SZ_XB    = (size_t)S_LEN * HDIM * 2;
constexpr size_t OFF_WQKV = OFF_XB + SZ_XB;             // f16[3*768*768]; later PL
constexpr size_t SZ_WQKV  = (size_t)3 * HDIM * HDIM * 2;
constexpr size_t OFF_WO   = OFF_WQKV + SZ_WQKV;         // f16[768*768]
constexpr size_t SZ_WO    = (size_t)HDIM * HDIM * 2;
constexpr size_t OFF_Q    = OFF_WO + SZ_WO;             // f16[12][4096][64]
constexpr size_t SZ_HD    = (size_t)NHEAD * S_LEN * DHEAD * 2;
constexpr size_t OFF_K    = OFF_Q + SZ_HD;              // f16[12][4096][64] compacted
constexpr size_t OFF_VT   = OFF_K + SZ_HD;              // f16[12][64][4096] transposed+permuted V
constexpr size_t OFF_VR   = OFF_VT + SZ_HD;             // (was V rows) now PO split0
constexpr size_t OFF_PO1  = OFF_VR + SZ_HD;             // f16[12][4096][64] PO split1

// ---------------- prep: fp32->fp16 convert + mask compaction (inverse map) ----------------
__global__ __launch_bounds__(256) void k_prep(const float* __restrict__ x,
                                              const float* __restrict__ wq,
                                              const float* __restrict__ wk,
                                              const float* __restrict__ wv,
                                              const float* __restrict__ wo,
                                              const int* __restrict__ mi,
                                              f16* __restrict__ dst,
                                              int* __restrict__ ridx,
                                              int* __restrict__ meta) {
  __shared__ int s_flag;
  __shared__ int s_cnt[256];
  const int b = blockIdx.x, tid = threadIdx.x;
  if (b < 5376) {
    int i = b * 256 + tid;                   // 1376256 float4 units
    const float* src; int off;
    if (i < 786432) { src = x; off = i; }
    else {
      int j = i - 786432;
      int w = j / 147456;
      off = j - w * 147456;
      src = (w == 0) ? wq : (w == 1) ? wk : (w == 2) ? wv : wo;
    }
    float4 v = ((const float4*)src)[off];
    f16x4 h;
    h[0] = (f16)v.x; h[1] = (f16)v.y; h[2] = (f16)v.z; h[3] = (f16)v.w;
    ((f16x4*)dst)[i] = h;
    return;
  }
  // ---- mask block ----
  if (tid == 0) s_flag = 1;
  __syncthreads();
  int bad = 0;
  #pragma unroll
  for (int k = 0; k < 4; ++k) {
    int v = mi[k * 256 + tid];
    if (v != 0 && v != 1) bad = 1;
  }
  if (bad) atomicAnd(&s_flag, 0);
  __syncthreads();
  const int isInt = s_flag;
  const unsigned char* mu8 = (const unsigned char*)mi;
  int keep[16]; int cnt = 0;
  const int s0 = tid * 16;
  #pragma unroll
  for (int k = 0; k < 16; ++k) {
    int mval = isInt ? mi[s0 + k] : (int)mu8[s0 + k];
    keep[k] = (mval == 0) ? 1 : 0;           // True => masked out (excluded)
    cnt += keep[k];
    ridx[s0 + k] = 0;                        // zero-fill inverse map (pad-safe)
  }
  s_cnt[tid] = cnt;
  __syncthreads();
  for (int off = 1; off < 256; off <<= 1) {
    int t = (tid >= off) ? s_cnt[tid - off] : 0;
    __syncthreads();
    s_cnt[tid] += t;
    __syncthreads();
  }
  int base = s_cnt[tid] - cnt;               // exclusive prefix
  #pragma unroll
  for (int k = 0; k < 16; ++k) {
    if (keep[k]) { ridx[base] = s0 + k; ++base; }
  }
  if (tid == 255) meta[0] = s_cnt[255];
}

// ---------------- fused QKV projection GEMM + V-transpose epilogue (k_vt folded in) -----
// mat==2 blocks hold the full 128-key x (2 heads x 64 d) V sub-tile in regs; they write
// Vtc[h][d][p] (k_vt's key-bit 2<->3 permuted layout) directly via an in-LDS transpose.
// mat==1 blocks zero K pad rows [kc,kcp) in their store guard. k_vt kernel + Vrow
// round-trip (write+cold-read of 3.1MB each) eliminated.
__global__ __launch_bounds__(256) void k_qkv(
    const f16* __restrict__ xb, const f16* __restrict__ wqkv,
    const float* __restrict__ bq, const float* __restrict__ bk, const float* __restrict__ bv,
    const int* __restrict__ ridx, const int* __restrict__ meta,
    f16* __restrict__ Qh, f16* __restrict__ Kc, f16* __restrict__ Vtc) {
  __shared__ __attribute__((aligned(16))) f16 lA[128 * 32];
  __shared__ __attribute__((aligned(16))) f16 lB[128 * 32];
  __shared__ __attribute__((aligned(16))) f16 lT[64 * 132];   // V-transpose bounce (16.9KB)
  const int tid = threadIdx.x;
  const int wid = tid >> 6, lane = tid & 63;
  const int hf = lane >> 5, l31 = lane & 31;
  const int wm = wid >> 1, wn = wid & 1;
  const int tn = blockIdx.x;
  const int m0 = blockIdx.y * 128;
  const int mat = tn / 6;
  const int nb = (tn % 6) * 128;
  const int kc = meta[0];
  const int kcp = (kc + 63) & ~63;
  if (mat != 0 && m0 >= kc) return;          // fully-pad K/V tile
  const f16* wbase = wqkv + (size_t)mat * HDIM * HDIM;

  const int ar0 = tid >> 2, ar1 = 64 + (tid >> 2);
  const f16* asrc0;
  const f16* asrc1;
  if (mat == 0) {
    asrc0 = xb + (size_t)(m0 + ar0) * HDIM;
    asrc1 = xb + (size_t)(m0 + ar1) * HDIM;
  } else {
    int g0 = (m0 + ar0 < kc) ? ridx[m0 + ar0] : 0;
    int g1 = (m0 + ar1 < kc) ? ridx[m0 + ar1] : 0;
    asrc0 = xb + (size_t)g0 * HDIM;
    asrc1 = xb + (size_t)g1 * HDIM;
  }
  const int slot = tid & 3;
  const int gs0 = slot ^ swz4(ar0);
  const int gs1 = slot ^ swz4(ar1);

  f32x16 acc[2][2] = {};

  for (int k0 = 0; k0 < HDIM; k0 += 32) {
    async_copy16((const char*)(asrc0 + k0) + gs0 * 16, (char*)lA + (wid * 64) * 16);
    async_copy16((const char*)(asrc1 + k0) + gs1 * 16, (char*)lA + (256 + wid * 64) * 16);
    async_copy16((const char*)(wbase + (size_t)(nb + ar0) * HDIM + k0) + gs0 * 16,
                 (char*)lB + (wid * 64) * 16);
    async_copy16((const char*)(wbase + (size_t)(nb + ar1) * HDIM + k0) + gs1 * 16,
                 (char*)lB + (256 + wid * 64) * 16);
    __syncthreads();
    #pragma unroll
    for (int kk = 0; kk < 2; ++kk) {
      f16x8 af[2], bf[2];
      #pragma unroll
      for (int mi = 0; mi < 2; ++mi) {
        int row = wm * 64 + mi * 32 + l31;
        af[mi] = *(const f16x8*)&lA[row * 32 + (((kk * 2 + hf) ^ swz4(row)) * 8)];
      }
      #pragma unroll
      for (int ni = 0; ni < 2; ++ni) {
        int row = wn * 64 + ni * 32 + l31;
        bf[ni] = *(const f16x8*)&lB[row * 32 + (((kk * 2 + hf) ^ swz4(row)) * 8)];
      }
      #pragma unroll
      for (int mi = 0; mi < 2; ++mi)
        #pragma unroll
        for (int ni = 0; ni < 2; ++ni)
          acc[mi][ni] = __builtin_amdgcn_mfma_f32_32x32x16_f16(af[mi], bf[ni], acc[mi][ni], 0, 0, 0);
    }
    __syncthreads();
  }

  if (mat == 2) {
    // ---- fused V epilogue: transpose+permute to Vtc[h][d][p] via lT ----
    const float* bias = bv;
    #pragma unroll
    for (int pass = 0; pass < 2; ++pass) {     // pass == head_local == wn
      __syncthreads();
      if (wn == pass) {
        #pragma unroll
        for (int ni = 0; ni < 2; ++ni) {
          const int n = nb + wn * 64 + ni * 32 + l31;
          const float bn = bias[n];
          const int dloc = ni * 32 + l31;
          #pragma unroll
          for (int mi = 0; mi < 2; ++mi) {
            #pragma unroll
            for (int rg = 0; rg < 4; ++rg) {   // 4 consecutive s per group
              const int sbase = wm * 64 + mi * 32 + 8 * rg + 4 * hf;
              f16x4 v4;
              #pragma unroll
              for (int j = 0; j < 4; ++j) {
                const int s = m0 + sbase + j;
                v4[j] = (s < kc) ? (f16)(acc[mi][ni][rg * 4 + j] + bn) : (f16)0.f;
              }
              *(f16x4*)&lT[dloc * 132 + sbase] = v4;
            }
          }
        }
      }
      __syncthreads();
      const int headg = (nb >> 6) + pass;
      // 64 d x 16 chunks of 8 keys, k_vt's within-16 bit-2<->3 swap:
      for (int u = tid; u < 1024; u += 256) {
        const int d = u >> 4, p8 = u & 15;
        const int base16 = (p8 >> 1) * 16, half = p8 & 1;
        f16x4 lo = *(const f16x4*)&lT[d * 132 + base16 + half * 4];
        f16x4 hi = *(const f16x4*)&lT[d * 132 + base16 + 8 + half * 4];
        f16x8 o;
        o[0] = lo[0]; o[1] = lo[1]; o[2] = lo[2]; o[3] = lo[3];
        o[4] = hi[0]; o[5] = hi[1]; o[6] = hi[2]; o[7] = hi[3];
        *(f16x8*)&Vtc[((size_t)headg * DHEAD + d) * S_LEN + m0 + p8 * 8] = o;
      }
    }
    return;
  }

  const float* bias = (mat == 0) ? bq : bk;
  const float qscale = 0.125f * 1.44269504088896341f;  // 1/sqrt(64) * log2(e)
  #pragma unroll
  for (int mi = 0; mi < 2; ++mi) {
    #pragma unroll
    for (int ni = 0; ni < 2; ++ni) {
      int n = nb + wn * 64 + ni * 32 + l31;
      int head = n >> 6, d = n & 63;
      float b = bias[n];
      #pragma unroll
      for (int reg = 0; reg < 16; ++reg) {
        int s = m0 + wm * 64 + mi * 32 + (reg & 3) + 8 * (reg >> 2) + 4 * hf;
        float val = acc[mi][ni][reg] + b;
        if (mat == 0) {
          Qh[((size_t)head * S_LEN + s) * DHEAD + d] = (f16)(val * qscale);
        } else if (s < kc) {
          Kc[((size_t)head * S_LEN + s) * DHEAD + d] = (f16)val;
        } else if (s < kcp) {
          Kc[((size_t)head * S_LEN + s) * DHEAD + d] = (f16)0.f;   // K pad rows -> P=1
        }
      }
    }
  }
}

// ---------------- flash attention: R3 anchor (2-buf stage-ahead, XCD-clustered) ----------
__global__ __launch_bounds__(256, 3) void k_attn(
    const f16* __restrict__ Qh, const f16* __restrict__ Kc, const f16* __restrict__ Vtc,
    const int* __restrict__ meta, f16* __restrict__ PO0, f16* __restrict__ PO1,
    float* __restrict__ PL) {
  __shared__ __attribute__((aligned(16))) f16 lK[2][64 * 64];   // [buf][key][d] swizzled
  __shared__ __attribute__((aligned(16))) f16 lV[2][64 * 64];   // [buf][d][rho] swizzled
  const int tid = threadIdx.x;
  const int wid = tid >> 6, lane = tid & 63;
  const int hf = lane >> 5, l31 = lane & 31, r7 = l31 & 7;

  const int lid = blockIdx.x;
  const int w = ((lid & 7) * 96) + (lid >> 3);
  const int head = w >> 6;
  const int rem = w & 63;
  const int split = rem >> 5;
  const int q0 = (rem & 31) * 128 + wid * 32;

  const int kc = meta[0];
  const int nkt = (kc + 63) >> 6;
  const int th = nkt >> 1;
  const int t0 = split ? th : 0;
  const int t1 = split ? nkt : th;

  const f16* Qp = Qh + ((size_t)head * S_LEN + q0 + l31) * DHEAD;
  f16x8 qf[4];
  #pragma unroll
  for (int dc = 0; dc < 4; ++dc) qf[dc] = *(const f16x8*)(Qp + dc * 16 + hf * 8);

  f32x16 accO[2] = {};
  float ls0 = 0.f, ls1 = 0.f, ls2 = 0.f, ls3 = 0.f;

  const char* kbase = (const char*)(Kc + (size_t)head * S_LEN * DHEAD);
  const char* vbase = (const char*)(Vtc + (size_t)head * DHEAD * S_LEN);

  const int c0row = tid >> 3,         c0slot = tid & 7;
  const int c1row = (256 + tid) >> 3, c1slot = tid & 7;
  const int gs0 = c0slot ^ (c0row & 7);
  const int gs1 = c1slot ^ (c1row & 7);

  auto stage = [&](int t, int buf) {
    const int j0 = t * 64;
    async_copy16(kbase + (size_t)(j0 + c0row) * 128 + gs0 * 16,
                 (char*)&lK[buf][0] + (wid * 64) * 16);
    async_copy16(vbase + (size_t)c0row * (S_LEN * 2) + (size_t)j0 * 2 + gs0 * 16,
                 (char*)&lV[buf][0] + (wid * 64) * 16);
    async_copy16(kbase + (size_t)(j0 + c1row) * 128 + gs1 * 16,
                 (char*)&lK[buf][0] + (256 + wid * 64) * 16);
    async_copy16(vbase + (size_t)c1row * (S_LEN * 2) + (size_t)j0 * 2 + gs1 * 16,
                 (char*)&lV[buf][0] + (256 + wid * 64) * 16);
  };

  int cur = 0;
  if (t0 < t1) {
    stage(t0, 0);
    __syncthreads();
  }

  for (int t = t0; t < t1; ++t) {
    const bool more = (t + 1 < t1);
    if (more) stage(t + 1, cur ^ 1);

    #pragma unroll
    for (int mh = 0; mh < 2; ++mh) {
      f16x8 af[4];
      const int arow = mh * 32 + l31;
      #pragma unroll
      for (int dc = 0; dc < 4; ++dc)
        af[dc] = *(const f16x8*)&lK[cur][arow * 64 + ((((dc << 1) | hf) ^ r7) * 8)];
      f32x16 s = {};
      #pragma unroll
      for (int dc = 0; dc < 4; ++dc)
        s = __builtin_amdgcn_mfma_f32_32x32x16_f16(af[dc], qf[dc], s, 0, 0, 0);
      #pragma unroll
      for (int u = 0; u < 16; ++u) {
        s[u] = fast_exp2(s[u]);
        if ((u & 3) == 0) ls0 += s[u];
        else if ((u & 3) == 1) ls1 += s[u];
        else if ((u & 3) == 2) ls2 += s[u];
        else ls3 += s[u];
      }
      #pragma unroll
      for (int cc = 0; cc < 2; ++cc) {
        f16x8 pf;
        #pragma unroll
        for (int u = 0; u < 8; ++u) pf[u] = (f16)s[8 * cc + u];
        const int c2 = mh * 2 + cc;
        #pragma unroll
        for (int dh = 0; dh < 2; ++dh) {
          const int vrow = dh * 32 + l31;
          f16x8 vf = *(const f16x8*)&lV[cur][vrow * 64 + ((((c2 << 1) | hf) ^ r7) * 8)];
          accO[dh] = __builtin_amdgcn_mfma_f32_32x32x16_f16(pf, vf, accO[dh], 0, 0, 0);
        }
      }
    }

    if (more) {
      __syncthreads();
      cur ^= 1;
    }
  }

  float lsum = (ls0 + ls1) + (ls2 + ls3);
  lsum += __shfl_xor(lsum, 32);
  if (split == 1) lsum -= (float)(nkt * 64 - kc);
  if (hf == 0)
    PL[((size_t)split * NHEAD + head) * S_LEN + q0 + l31] = lsum;

  // coalesced PO store via LDS bounce (reuse dead lK)
  __syncthreads();
  f16* ost = (f16*)lK;
  #pragma unroll
  for (int dh = 0; dh < 2; ++dh)
    #pragma unroll
    for (int reg = 0; reg < 16; ++reg) {
      int row = (reg & 3) + 8 * (reg >> 2) + 4 * hf;
      ost[wid * 2048 + row * 64 + dh * 32 + l31] = (f16)accO[dh][reg];
    }
  f16* PO = split ? PO1 : PO0;
  const f16* osrc = ost + wid * 2048;
  #pragma unroll
  for (int p = 0; p < 4; ++p) {
    int row = p * 8 + (lane >> 3), sl = lane & 7;
    f16x8 v = *(const f16x8*)&osrc[row * 64 + sl * 8];
    *(f16x8*)&PO[((size_t)head * S_LEN + q0 + row) * DHEAD + sl * 8] = v;
  }
}

// ---------------- output projection GEMM: 128x64 tiles, BK=64, 384 blocks, XCD-grouped ---
__global__ __launch_bounds__(256) void k_out(
    const f16* __restrict__ PO0, const f16* __restrict__ PO1,
    const float* __restrict__ PL, const f16* __restrict__ wo,
    const float* __restrict__ bo, float* __restrict__ out) {
  __shared__ __attribute__((aligned(16))) f16 lA[128 * 64];   // 16KB
  __shared__ __attribute__((aligned(16))) f16 lB[64 * 64];    // 8KB
  __shared__ float linv[NHEAD * 128];
  const int tid = threadIdx.x;
  const int wid = tid >> 6, lane = tid & 63;
  const int hf = lane >> 5, l31 = lane & 31;
  const int wm = wid >> 1, wn = wid & 1;     // 2x2 waves of 64m x 32n
  const int lid = blockIdx.x;
  const int w = ((lid & 7) * 48) + (lid >> 3);   // XCD-grouped: 48 units/XCD share m-tiles
  const int nb = (w % 12) * 64;
  const int m0 = (w / 12) * 128;

  for (int i = tid; i < NHEAD * 128; i += 256) {
    int h = i >> 7, r = i & 127;
    float l = PL[(size_t)h * S_LEN + m0 + r] + PL[(size_t)(NHEAD + h) * S_LEN + m0 + r];
    linv[i] = 1.0f / l;
  }
  __syncthreads();

  f32x16 acc[2] = {};   // [mi]

  for (int head = 0; head < NHEAD; ++head) {   // BK=64 == one head per step
    #pragma unroll
    for (int it = 0; it < 4; ++it) {
      int c = it * 256 + tid;
      int row = c >> 3, slot = c & 7;
      int gs = slot ^ (row & 7);
      size_t pi = ((size_t)head * S_LEN + m0 + row) * DHEAD + gs * 8;
      f16x8 a0 = *(const f16x8*)(PO0 + pi);
      f16x8 a1 = *(const f16x8*)(PO1 + pi);
      float il = linv[head * 128 + row];
      f16x8 av;
      #pragma unroll
      for (int u = 0; u < 8; ++u) av[u] = (f16)(((float)a0[u] + (float)a1[u]) * il);
      *(f16x8*)&lA[c * 8] = av;
    }
    #pragma unroll
    for (int it = 0; it < 2; ++it) {
      int c = it * 256 + tid;
      int row = c >> 3, slot = c & 7;
      int gs = slot ^ (row & 7);
      async_copy16((const char*)(wo + (size_t)(nb + row) * HDIM + head * 64) + gs * 16,
                   (char*)lB + (it * 256 + wid * 64) * 16);
    }
    __syncthreads();
    #pragma unroll
    for (int kk = 0; kk < 4; ++kk) {
      f16x8 af[2], bf;
      #pragma unroll
      for (int mi = 0; mi < 2; ++mi) {
        int row = wm * 64 + mi * 32 + l31;
        af[mi] = *(const f16x8*)&lA[row * 64 + ((((kk << 1) | hf) ^ (row & 7)) * 8)];
      }
      int rb = wn * 32 + l31;
      bf = *(const f16x8*)&lB[rb * 64 + ((((kk << 1) | hf) ^ (rb & 7)) * 8)];
      #pragma unroll
      for (int mi = 0; mi < 2; ++mi)
        acc[mi] = __builtin_amdgcn_mfma_f32_32x32x16_f16(af[mi], bf, acc[mi], 0, 0, 0);
    }
    __syncthreads();
  }

  const int n = nb + wn * 32 + l31;
  const float b = bo[n];
  #pragma unroll
  for (int mi = 0; mi < 2; ++mi) {
    #pragma unroll
    for (int reg = 0; reg < 16; ++reg) {
      int s = m0 + wm * 64 + mi * 32 + (reg & 3) + 8 * (reg >> 2) + 4 * hf;
      out[(size_t)s * HDIM + n] = acc[mi][reg] + b;
    }
  }
}

extern "C" void kernel_launch(void* const* d_in, const int* in_sizes, int n_in,
                              void* d_out, int out_size, void* d_ws, size_t ws_size,
                              hipStream_t stream) {
  const float* x  = (const float*)d_in[0];
  const float* Wq = (const float*)d_in[1];
  const float* bq = (const float*)d_in[2];
  const float* Wk = (const float*)d_in[3];
  const float* bk = (const float*)d_in[4];
  const float* Wv = (const float*)d_in[5];
  const float* bv = (const float*)d_in[6];
  const float* Wo = (const float*)d_in[7];
  const float* bo = (const float*)d_in[8];
  const int*   mask = (const int*)d_in[9];
  float* out = (float*)d_out;

  char* ws = (char*)d_ws;
  int* meta  = (int*)(ws + OFF_META);
  int* ridx  = (int*)(ws + OFF_RIDX);
  f16* xb    = (f16*)(ws + OFF_XB);
  f16* wqkv  = (f16*)(ws + OFF_WQKV);
  f16* wob   = (f16*)(ws + OFF_WO);
  f16* Qh    = (f16*)(ws + OFF_Q);
  f16* Kc    = (f16*)(ws + OFF_K);
  f16* Vtc   = (f16*)(ws + OFF_VT);
  f16* PO0   = (f16*)(ws + OFF_VR);
  f16* PO1   = (f16*)(ws + OFF_PO1);
  float* PL  = (float*)(ws + OFF_WQKV); // reuses wqkv after k_qkv

  k_prep<<<dim3(5377), 256, 0, stream>>>(x, Wq, Wk, Wv, Wo, mask, xb, ridx, meta);
  k_qkv<<<dim3(18, 32), 256, 0, stream>>>(xb, wqkv, bq, bk, bv, ridx, meta, Qh, Kc, Vtc);
  k_attn<<<dim3(768), 256, 0, stream>>>(Qh, Kc, Vtc, meta, PO0, PO1, PL);
  k_out<<<dim3(384), 256, 0, stream>>>(PO0, PO1, PL, wob, bo, out);
}

// Round 10
// 169.043 us; speedup vs baseline: 1.0554x; 1.0112x over previous
//
#include <hip/hip_runtime.h>
#include <stdint.h>

#define S_LEN 4096
#define HDIM  768
#define NHEAD 12
#define DHEAD 64

typedef _Float16 f16;
typedef __attribute__((ext_vector_type(8)))  _Float16 f16x8;
typedef __attribute__((ext_vector_type(4)))  _Float16 f16x4;
typedef __attribute__((ext_vector_type(4)))  float    f32x4;
typedef __attribute__((ext_vector_type(16))) float    f32x16;

typedef __attribute__((address_space(1))) void gv_t;
typedef __attribute__((address_space(3))) void lv_t;

__device__ __forceinline__ void async_copy16(const void* g, void* l) {
  __builtin_amdgcn_global_load_lds((gv_t*)g, (lv_t*)l, 16, 0, 0);
}

__device__ __forceinline__ float fast_exp2(float x) {
#if __has_builtin(__builtin_amdgcn_exp2f)
  return __builtin_amdgcn_exp2f(x);
#else
  return exp2f(x);
#endif
}

__device__ __forceinline__ int swz4(int row) { return (row ^ (row >> 2)) & 3; }

// ---------------- workspace layout (heavy reuse) ----------------
constexpr size_t OFF_META = 0;                          // int kcount
constexpr size_t OFF_RIDX = 256;                        // int[4096] inverse map p->s
constexpr size_t OFF_XB   = 65536;                      // f16 x[4096*768]
constexpr size_t SZ_XB    = (size_t)S_LEN * HDIM * 2;
constexpr size_t OFF_WQKV = OFF_XB + SZ_XB;             // f16[3*768*768]
constexpr size_t SZ_WQKV  = (size_t)3 * HDIM * HDIM * 2;
constexpr size_t OFF_WO   = OFF_WQKV + SZ_WQKV;         // f16[768*768]
constexpr size_t SZ_WO    = (size_t)HDIM * HDIM * 2;
constexpr size_t OFF_Q    = OFF_WO + SZ_WO;             // f16[12][4096][64]
constexpr size_t SZ_HD    = (size_t)NHEAD * S_LEN * DHEAD * 2;
constexpr size_t OFF_K    = OFF_Q + SZ_HD;              // f16[12][4096][64] compacted
constexpr size_t OFF_VT   = OFF_K + SZ_HD;              // f16[12][64][4096] transposed+permuted V
constexpr size_t OFF_PO   = OFF_VT + SZ_HD;             // f16[12][4096][64] normalized O

// ---------------- prep: fp32->fp16 convert + mask compaction (inverse map) ----------------
__global__ __launch_bounds__(256) void k_prep(const float* __restrict__ x,
                                              const float* __restrict__ wq,
                                              const float* __restrict__ wk,
                                              const float* __restrict__ wv,
                                              const float* __restrict__ wo,
                                              const int* __restrict__ mi,
                                              f16* __restrict__ dst,
                                              int* __restrict__ ridx,
                                              int* __restrict__ meta) {
  __shared__ int s_flag;
  __shared__ int s_cnt[256];
  const int b = blockIdx.x, tid = threadIdx.x;
  if (b < 5376) {
    int i = b * 256 + tid;                   // 1376256 float4 units
    const float* src; int off;
    if (i < 786432) { src = x; off = i; }
    else {
      int j = i - 786432;
      int w = j / 147456;
      off = j - w * 147456;
      src = (w == 0) ? wq : (w == 1) ? wk : (w == 2) ? wv : wo;
    }
    float4 v = ((const float4*)src)[off];
    f16x4 h;
    h[0] = (f16)v.x; h[1] = (f16)v.y; h[2] = (f16)v.z; h[3] = (f16)v.w;
    ((f16x4*)dst)[i] = h;
    return;
  }
  // ---- mask block ----
  if (tid == 0) s_flag = 1;
  __syncthreads();
  int bad = 0;
  #pragma unroll
  for (int k = 0; k < 4; ++k) {
    int v = mi[k * 256 + tid];
    if (v != 0 && v != 1) bad = 1;
  }
  if (bad) atomicAnd(&s_flag, 0);
  __syncthreads();
  const int isInt = s_flag;
  const unsigned char* mu8 = (const unsigned char*)mi;
  int keep[16]; int cnt = 0;
  const int s0 = tid * 16;
  #pragma unroll
  for (int k = 0; k < 16; ++k) {
    int mval = isInt ? mi[s0 + k] : (int)mu8[s0 + k];
    keep[k] = (mval == 0) ? 1 : 0;           // True => masked out (excluded)
    cnt += keep[k];
    ridx[s0 + k] = 0;                        // zero-fill inverse map (pad-safe)
  }
  s_cnt[tid] = cnt;
  __syncthreads();
  for (int off = 1; off < 256; off <<= 1) {
    int t = (tid >= off) ? s_cnt[tid - off] : 0;
    __syncthreads();
    s_cnt[tid] += t;
    __syncthreads();
  }
  int base = s_cnt[tid] - cnt;               // exclusive prefix
  #pragma unroll
  for (int k = 0; k < 16; ++k) {
    if (keep[k]) { ridx[base] = s0 + k; ++base; }
  }
  if (tid == 255) meta[0] = s_cnt[255];
}

// ---------------- fused QKV projection GEMM + V-transpose epilogue (k_vt folded in) -----
__global__ __launch_bounds__(256) void k_qkv(
    const f16* __restrict__ xb, const f16* __restrict__ wqkv,
    const float* __restrict__ bq, const float* __restrict__ bk, const float* __restrict__ bv,
    const int* __restrict__ ridx, const int* __restrict__ meta,
    f16* __restrict__ Qh, f16* __restrict__ Kc, f16* __restrict__ Vtc) {
  __shared__ __attribute__((aligned(16))) f16 lA[128 * 32];
  __shared__ __attribute__((aligned(16))) f16 lB[128 * 32];
  __shared__ __attribute__((aligned(16))) f16 lT[64 * 132];   // V-transpose bounce (16.9KB)
  const int tid = threadIdx.x;
  const int wid = tid >> 6, lane = tid & 63;
  const int hf = lane >> 5, l31 = lane & 31;
  const int wm = wid >> 1, wn = wid & 1;
  const int tn = blockIdx.x;
  const int m0 = blockIdx.y * 128;
  const int mat = tn / 6;
  const int nb = (tn % 6) * 128;
  const int kc = meta[0];
  const int kcp = (kc + 63) & ~63;
  if (mat != 0 && m0 >= kc) return;          // fully-pad K/V tile
  const f16* wbase = wqkv + (size_t)mat * HDIM * HDIM;

  const int ar0 = tid >> 2, ar1 = 64 + (tid >> 2);
  const f16* asrc0;
  const f16* asrc1;
  if (mat == 0) {
    asrc0 = xb + (size_t)(m0 + ar0) * HDIM;
    asrc1 = xb + (size_t)(m0 + ar1) * HDIM;
  } else {
    int g0 = (m0 + ar0 < kc) ? ridx[m0 + ar0] : 0;
    int g1 = (m0 + ar1 < kc) ? ridx[m0 + ar1] : 0;
    asrc0 = xb + (size_t)g0 * HDIM;
    asrc1 = xb + (size_t)g1 * HDIM;
  }
  const int slot = tid & 3;
  const int gs0 = slot ^ swz4(ar0);
  const int gs1 = slot ^ swz4(ar1);

  f32x16 acc[2][2] = {};

  for (int k0 = 0; k0 < HDIM; k0 += 32) {
    async_copy16((const char*)(asrc0 + k0) + gs0 * 16, (char*)lA + (wid * 64) * 16);
    async_copy16((const char*)(asrc1 + k0) + gs1 * 16, (char*)lA + (256 + wid * 64) * 16);
    async_copy16((const char*)(wbase + (size_t)(nb + ar0) * HDIM + k0) + gs0 * 16,
                 (char*)lB + (wid * 64) * 16);
    async_copy16((const char*)(wbase + (size_t)(nb + ar1) * HDIM + k0) + gs1 * 16,
                 (char*)lB + (256 + wid * 64) * 16);
    __syncthreads();
    #pragma unroll
    for (int kk = 0; kk < 2; ++kk) {
      f16x8 af[2], bf[2];
      #pragma unroll
      for (int mi = 0; mi < 2; ++mi) {
        int row = wm * 64 + mi * 32 + l31;
        af[mi] = *(const f16x8*)&lA[row * 32 + (((kk * 2 + hf) ^ swz4(row)) * 8)];
      }
      #pragma unroll
      for (int ni = 0; ni < 2; ++ni) {
        int row = wn * 64 + ni * 32 + l31;
        bf[ni] = *(const f16x8*)&lB[row * 32 + (((kk * 2 + hf) ^ swz4(row)) * 8)];
      }
      #pragma unroll
      for (int mi = 0; mi < 2; ++mi)
        #pragma unroll
        for (int ni = 0; ni < 2; ++ni)
          acc[mi][ni] = __builtin_amdgcn_mfma_f32_32x32x16_f16(af[mi], bf[ni], acc[mi][ni], 0, 0, 0);
    }
    __syncthreads();
  }

  if (mat == 2) {
    // ---- fused V epilogue: transpose+permute to Vtc[h][d][p] via lT ----
    const float* bias = bv;
    #pragma unroll
    for (int pass = 0; pass < 2; ++pass) {     // pass == head_local == wn
      __syncthreads();
      if (wn == pass) {
        #pragma unroll
        for (int ni = 0; ni < 2; ++ni) {
          const int n = nb + wn * 64 + ni * 32 + l31;
          const float bn = bias[n];
          const int dloc = ni * 32 + l31;
          #pragma unroll
          for (int mi = 0; mi < 2; ++mi) {
            #pragma unroll
            for (int rg = 0; rg < 4; ++rg) {   // 4 consecutive s per group
              const int sbase = wm * 64 + mi * 32 + 8 * rg + 4 * hf;
              f16x4 v4;
              #pragma unroll
              for (int j = 0; j < 4; ++j) {
                const int s = m0 + sbase + j;
                v4[j] = (s < kc) ? (f16)(acc[mi][ni][rg * 4 + j] + bn) : (f16)0.f;
              }
              *(f16x4*)&lT[dloc * 132 + sbase] = v4;
            }
          }
        }
      }
      __syncthreads();
      const int headg = (nb >> 6) + pass;
      // 64 d x 16 chunks of 8 keys, k_vt's within-16 bit-2<->3 swap:
      for (int u = tid; u < 1024; u += 256) {
        const int d = u >> 4, p8 = u & 15;
        const int base16 = (p8 >> 1) * 16, half = p8 & 1;
        f16x4 lo = *(const f16x4*)&lT[d * 132 + base16 + half * 4];
        f16x4 hi = *(const f16x4*)&lT[d * 132 + base16 + 8 + half * 4];
        f16x8 o;
        o[0] = lo[0]; o[1] = lo[1]; o[2] = lo[2]; o[3] = lo[3];
        o[4] = hi[0]; o[5] = hi[1]; o[6] = hi[2]; o[7] = hi[3];
        *(f16x8*)&Vtc[((size_t)headg * DHEAD + d) * S_LEN + m0 + p8 * 8] = o;
      }
    }
    return;
  }

  const float* bias = (mat == 0) ? bq : bk;
  const float qscale = 0.125f * 1.44269504088896341f;  // 1/sqrt(64) * log2(e)
  #pragma unroll
  for (int mi = 0; mi < 2; ++mi) {
    #pragma unroll
    for (int ni = 0; ni < 2; ++ni) {
      int n = nb + wn * 64 + ni * 32 + l31;
      int head = n >> 6, d = n & 63;
      float b = bias[n];
      #pragma unroll
      for (int reg = 0; reg < 16; ++reg) {
        int s = m0 + wm * 64 + mi * 32 + (reg & 3) + 8 * (reg >> 2) + 4 * hf;
        float val = acc[mi][ni][reg] + b;
        if (mat == 0) {
          Qh[((size_t)head * S_LEN + s) * DHEAD + d] = (f16)(val * qscale);
        } else if (s < kc) {
          Kc[((size_t)head * S_LEN + s) * DHEAD + d] = (f16)val;
        } else if (s < kcp) {
          Kc[((size_t)head * S_LEN + s) * DHEAD + d] = (f16)0.f;   // K pad rows -> P=1
        }
      }
    }
  }
}

// ---------------- flash attention: single-split, 128-thread blocks, normalized-O output --
// vs R9: no key-split. 768 blocks = 12 heads x 64 q-blocks (2 waves x 32q), each covering
// ALL keys -> full softmax denominator is known in-kernel, so O is normalized here and
// PO is final f16. Eliminates PO1 (6.3MB write + 6.3MB cold read), PL, and k_out's
// fp32 combine pass. 32.25KB LDS -> 4 blocks/CU: all 1536 waves co-resident, zero tail.
__global__ __launch_bounds__(128, 2) void k_attn(
    const f16* __restrict__ Qh, const f16* __restrict__ Kc, const f16* __restrict__ Vtc,
    const int* __restrict__ meta, f16* __restrict__ PO) {
  __shared__ __attribute__((aligned(16))) f16 lK[2][64 * 64];   // [buf][key][d] swizzled
  __shared__ __attribute__((aligned(16))) f16 lV[2][64 * 64];   // [buf][d][rho] swizzled
  __shared__ float lil[64];                                     // per-query 1/l (2 waves x 32)
  const int tid = threadIdx.x;            // 0..127
  const int wid = tid >> 6, lane = tid & 63;
  const int hf = lane >> 5, l31 = lane & 31, r7 = l31 & 7;

  // XCD head-clustering: 768 blocks, 96 contiguous work units per XCD (<=1.5 heads each).
  const int lid = blockIdx.x;
  const int w = ((lid & 7) * 96) + (lid >> 3);
  const int head = w >> 6;
  const int q0 = (w & 63) * 64 + wid * 32;   // wave's 32-query base

  const int kc = meta[0];
  const int nkt = (kc + 63) >> 6;

  // Q B-frags: lane n = q = l31, k = dc*16 + hf*8 + j  (held in regs whole kernel)
  const f16* Qp = Qh + ((size_t)head * S_LEN + q0 + l31) * DHEAD;
  f16x8 qf[4];
  #pragma unroll
  for (int dc = 0; dc < 4; ++dc) qf[dc] = *(const f16x8*)(Qp + dc * 16 + hf * 8);

  f32x16 accO[2] = {};     // [dh]: O columns dh*32+l31, rows = C-layout
  float ls0 = 0.f, ls1 = 0.f, ls2 = 0.f, ls3 = 0.f;

  const char* kbase = (const char*)(Kc + (size_t)head * S_LEN * DHEAD);
  const char* vbase = (const char*)(Vtc + (size_t)head * DHEAD * S_LEN);

  // 512 16B-chunks per 8KB tile, 128 threads -> 4 asyncs each for K and V
  const int crow = tid >> 3, cslot = tid & 7;
  const int gsc = cslot ^ (crow & 7);       // +it*16 rows keeps row&7 (16%8==0)

  auto stage = [&](int t, int buf) {
    const int j0 = t * 64;
    #pragma unroll
    for (int it = 0; it < 4; ++it) {
      const int row = it * 16 + crow;
      async_copy16(kbase + (size_t)(j0 + row) * 128 + gsc * 16,
                   (char*)&lK[buf][0] + (it * 128 + wid * 64) * 16);
      async_copy16(vbase + (size_t)row * (S_LEN * 2) + (size_t)j0 * 2 + gsc * 16,
                   (char*)&lV[buf][0] + (it * 128 + wid * 64) * 16);
    }
  };

  int cur = 0;
  stage(0, 0);
  __syncthreads();

  for (int t = 0; t < nkt; ++t) {
    const bool more = (t + 1 < nkt);
    if (more) stage(t + 1, cur ^ 1);

    #pragma unroll
    for (int mh = 0; mh < 2; ++mh) {
      f16x8 af[4];
      const int arow = mh * 32 + l31;
      #pragma unroll
      for (int dc = 0; dc < 4; ++dc)
        af[dc] = *(const f16x8*)&lK[cur][arow * 64 + ((((dc << 1) | hf) ^ r7) * 8)];
      f32x16 s = {};
      #pragma unroll
      for (int dc = 0; dc < 4; ++dc)
        s = __builtin_amdgcn_mfma_f32_32x32x16_f16(af[dc], qf[dc], s, 0, 0, 0);
      #pragma unroll
      for (int u = 0; u < 16; ++u) {
        s[u] = fast_exp2(s[u]);
        if ((u & 3) == 0) ls0 += s[u];
        else if ((u & 3) == 1) ls1 += s[u];
        else if ((u & 3) == 2) ls2 += s[u];
        else ls3 += s[u];
      }
      #pragma unroll
      for (int cc = 0; cc < 2; ++cc) {
        f16x8 pf;
        #pragma unroll
        for (int u = 0; u < 8; ++u) pf[u] = (f16)s[8 * cc + u];
        const int c2 = mh * 2 + cc;
        #pragma unroll
        for (int dh = 0; dh < 2; ++dh) {
          const int vrow = dh * 32 + l31;
          f16x8 vf = *(const f16x8*)&lV[cur][vrow * 64 + ((((c2 << 1) | hf) ^ r7) * 8)];
          accO[dh] = __builtin_amdgcn_mfma_f32_32x32x16_f16(pf, vf, accO[dh], 0, 0, 0);
        }
      }
    }

    if (more) {
      __syncthreads();
      cur ^= 1;
    }
  }

  float lsum = (ls0 + ls1) + (ls2 + ls3);
  lsum += __shfl_xor(lsum, 32);              // fold hf halves
  lsum -= (float)(nkt * 64 - kc);            // pad keys (zero K rows) contribute exp=1
  if (hf == 0) lil[wid * 32 + l31] = 1.0f / lsum;
  __syncthreads();                           // publishes lil; all lK/lV reads done

  // normalized, coalesced PO store via LDS bounce (reuse dead lK; 4KB per wave)
  f16* ost = (f16*)lK + wid * 2048;
  #pragma unroll
  for (int dh = 0; dh < 2; ++dh)
    #pragma unroll
    for (int reg = 0; reg < 16; ++reg) {
      int row = (reg & 3) + 8 * (reg >> 2) + 4 * hf;
      ost[row * 64 + dh * 32 + l31] = (f16)(accO[dh][reg] * lil[wid * 32 + row]);
    }
  #pragma unroll
  for (int p = 0; p < 4; ++p) {
    int row = p * 8 + (lane >> 3), sl = lane & 7;
    f16x8 v = *(const f16x8*)&ost[row * 64 + sl * 8];
    *(f16x8*)&PO[((size_t)head * S_LEN + q0 + row) * DHEAD + sl * 8] = v;
  }
}

// ---------------- output projection GEMM: single normalized PO, all-async staging --------
__global__ __launch_bounds__(256) void k_out(
    const f16* __restrict__ PO, const f16* __restrict__ wo,
    const float* __restrict__ bo, float* __restrict__ out) {
  __shared__ __attribute__((aligned(16))) f16 lA[128 * 64];   // 16KB
  __shared__ __attribute__((aligned(16))) f16 lB[64 * 64];    // 8KB
  const int tid = threadIdx.x;
  const int wid = tid >> 6, lane = tid & 63;
  const int hf = lane >> 5, l31 = lane & 31;
  const int wm = wid >> 1, wn = wid & 1;     // 2x2 waves of 64m x 32n
  const int lid = blockIdx.x;
  const int w = ((lid & 7) * 48) + (lid >> 3);   // XCD-grouped: 48 units/XCD share m-tiles
  const int nb = (w % 12) * 64;
  const int m0 = (w / 12) * 128;

  f32x16 acc[2] = {};   // [mi]

  for (int head = 0; head < NHEAD; ++head) {   // BK=64 == one head per step
    // A: PO rows (already normalized f16) via async; 1024 chunks
    #pragma unroll
    for (int it = 0; it < 4; ++it) {
      int c = it * 256 + tid;
      int row = c >> 3, slot = c & 7;
      int gs = slot ^ (row & 7);
      async_copy16((const char*)(PO + ((size_t)head * S_LEN + m0 + row) * DHEAD) + gs * 16,
                   (char*)lA + (it * 256 + wid * 64) * 16);
    }
    // B: wo rows (output cols) nb..nb+63, k-range head*64..+64; 512 chunks
    #pragma unroll
    for (int it = 0; it < 2; ++it) {
      int c = it * 256 + tid;
      int row = c >> 3, slot = c & 7;
      int gs = slot ^ (row & 7);
      async_copy16((const char*)(wo + (size_t)(nb + row) * HDIM + head * 64) + gs * 16,
                   (char*)lB + (it * 256 + wid * 64) * 16);
    }
    __syncthreads();
    #pragma unroll
    for (int kk = 0; kk < 4; ++kk) {
      f16x8 af[2], bf;
      #pragma unroll
      for (int mi = 0; mi < 2; ++mi) {
        int row = wm * 64 + mi * 32 + l31;
        af[mi] = *(const f16x8*)&lA[row * 64 + ((((kk << 1) | hf) ^ (row & 7)) * 8)];
      }
      int rb = wn * 32 + l31;
      bf = *(const f16x8*)&lB[rb * 64 + ((((kk << 1) | hf) ^ (rb & 7)) * 8)];
      #pragma unroll
      for (int mi = 0; mi < 2; ++mi)
        acc[mi] = __builtin_amdgcn_mfma_f32_32x32x16_f16(af[mi], bf, acc[mi], 0, 0, 0);
    }
    __syncthreads();
  }

  const int n = nb + wn * 32 + l31;
  const float b = bo[n];
  #pragma unroll
  for (int mi = 0; mi < 2; ++mi) {
    #pragma unroll
    for (int reg = 0; reg < 16; ++reg) {
      int s = m0 + wm * 64 + mi * 32 + (reg & 3) + 8 * (reg >> 2) + 4 * hf;
      out[(size_t)s * HDIM + n] = acc[mi][reg] + b;
    }
  }
}

extern "C" void kernel_launch(void* const* d_in, const int* in_sizes, int n_in,
                              void* d_out, int out_size, void* d_ws, size_t ws_size,
                              hipStream_t stream) {
  const float* x  = (const float*)d_in[0];
  const float* Wq = (const float*)d_in[1];
  const float* bq = (const float*)d_in[2];
  const float* Wk = (const float*)d_in[3];
  const float* bk = (const float*)d_in[4];
  const float* Wv = (const float*)d_in[5];
  const float* bv = (const float*)d_in[6];
  const float* Wo = (const float*)d_in[7];
  const float* bo = (const float*)d_in[8];
  const int*   mask = (const int*)d_in[9];
  float* out = (float*)d_out;

  char* ws = (char*)d_ws;
  int* meta  = (int*)(ws + OFF_META);
  int* ridx  = (int*)(ws + OFF_RIDX);
  f16* xb    = (f16*)(ws + OFF_XB);
  f16* wqkv  = (f16*)(ws + OFF_WQKV);
  f16* wob   = (f16*)(ws + OFF_WO);
  f16* Qh    = (f16*)(ws + OFF_Q);
  f16* Kc    = (f16*)(ws + OFF_K);
  f16* Vtc   = (f16*)(ws + OFF_VT);
  f16* PO    = (f16*)(ws + OFF_PO);

  k_prep<<<dim3(5377), 256, 0, stream>>>(x, Wq, Wk, Wv, Wo, mask, xb, ridx, meta);
  k_qkv<<<dim3(18, 32), 256, 0, stream>>>(xb, wqkv, bq, bk, bv, ridx, meta, Qh, Kc, Vtc);
  k_attn<<<dim3(768), 128, 0, stream>>>(Qh, Kc, Vtc, meta, PO);
  k_out<<<dim3(384), 256, 0, stream>>>(PO, wob, bo, out);
}

// Round 11
// 168.886 us; speedup vs baseline: 1.0564x; 1.0009x over previous
//
#include <hip/hip_runtime.h>
#include <stdint.h>

#define S_LEN 4096
#define HDIM  768
#define NHEAD 12
#define DHEAD 64

typedef _Float16 f16;
typedef __attribute__((ext_vector_type(8)))  _Float16 f16x8;
typedef __attribute__((ext_vector_type(4)))  _Float16 f16x4;
typedef __attribute__((ext_vector_type(4)))  float    f32x4;
typedef __attribute__((ext_vector_type(16))) float    f32x16;

typedef __attribute__((address_space(1))) void gv_t;
typedef __attribute__((address_space(3))) void lv_t;

__device__ __forceinline__ void async_copy16(const void* g, void* l) {
  __builtin_amdgcn_global_load_lds((gv_t*)g, (lv_t*)l, 16, 0, 0);
}

__device__ __forceinline__ float fast_exp2(float x) {
#if __has_builtin(__builtin_amdgcn_exp2f)
  return __builtin_amdgcn_exp2f(x);
#else
  return exp2f(x);
#endif
}

__device__ __forceinline__ int swz4(int row) { return (row ^ (row >> 2)) & 3; }

// ---------------- workspace layout (heavy reuse) ----------------
constexpr size_t OFF_META = 0;                          // int kcount
constexpr size_t OFF_RIDX = 256;                        // int[4096] inverse map p->s
constexpr size_t OFF_XB   = 65536;                      // f16 x[4096*768]
constexpr size_t SZ_XB    = (size_t)S_LEN * HDIM * 2;
constexpr size_t OFF_WQKV = OFF_XB + SZ_XB;             // f16[3*768*768]
constexpr size_t SZ_WQKV  = (size_t)3 * HDIM * HDIM * 2;
constexpr size_t OFF_WO   = OFF_WQKV + SZ_WQKV;         // f16[768*768]
constexpr size_t SZ_WO    = (size_t)HDIM * HDIM * 2;
constexpr size_t OFF_Q    = OFF_WO + SZ_WO;             // f16[12][4096][64]
constexpr size_t SZ_HD    = (size_t)NHEAD * S_LEN * DHEAD * 2;
constexpr size_t OFF_K    = OFF_Q + SZ_HD;              // f16[12][4096][64] compacted
constexpr size_t OFF_VT   = OFF_K + SZ_HD;              // f16[12][64][4096] transposed+permuted V
constexpr size_t OFF_PO   = OFF_VT + SZ_HD;             // f16[12][4096][64] normalized O

// ---------------- prep: fp32->fp16 convert + mask compaction (inverse map) ----------------
__global__ __launch_bounds__(256) void k_prep(const float* __restrict__ x,
                                              const float* __restrict__ wq,
                                              const float* __restrict__ wk,
                                              const float* __restrict__ wv,
                                              const float* __restrict__ wo,
                                              const int* __restrict__ mi,
                                              f16* __restrict__ dst,
                                              int* __restrict__ ridx,
                                              int* __restrict__ meta) {
  __shared__ int s_flag;
  __shared__ int s_cnt[256];
  const int b = blockIdx.x, tid = threadIdx.x;
  if (b < 5376) {
    int i = b * 256 + tid;                   // 1376256 float4 units
    const float* src; int off;
    if (i < 786432) { src = x; off = i; }
    else {
      int j = i - 786432;
      int w = j / 147456;
      off = j - w * 147456;
      src = (w == 0) ? wq : (w == 1) ? wk : (w == 2) ? wv : wo;
    }
    float4 v = ((const float4*)src)[off];
    f16x4 h;
    h[0] = (f16)v.x; h[1] = (f16)v.y; h[2] = (f16)v.z; h[3] = (f16)v.w;
    ((f16x4*)dst)[i] = h;
    return;
  }
  // ---- mask block ----
  if (tid == 0) s_flag = 1;
  __syncthreads();
  int bad = 0;
  #pragma unroll
  for (int k = 0; k < 4; ++k) {
    int v = mi[k * 256 + tid];
    if (v != 0 && v != 1) bad = 1;
  }
  if (bad) atomicAnd(&s_flag, 0);
  __syncthreads();
  const int isInt = s_flag;
  const unsigned char* mu8 = (const unsigned char*)mi;
  int keep[16]; int cnt = 0;
  const int s0 = tid * 16;
  #pragma unroll
  for (int k = 0; k < 16; ++k) {
    int mval = isInt ? mi[s0 + k] : (int)mu8[s0 + k];
    keep[k] = (mval == 0) ? 1 : 0;           // True => masked out (excluded)
    cnt += keep[k];
    ridx[s0 + k] = 0;                        // zero-fill inverse map (pad-safe)
  }
  s_cnt[tid] = cnt;
  __syncthreads();
  for (int off = 1; off < 256; off <<= 1) {
    int t = (tid >= off) ? s_cnt[tid - off] : 0;
    __syncthreads();
    s_cnt[tid] += t;
    __syncthreads();
  }
  int base = s_cnt[tid] - cnt;               // exclusive prefix
  #pragma unroll
  for (int k = 0; k < 16; ++k) {
    if (keep[k]) { ridx[base] = s0 + k; ++base; }
  }
  if (tid == 255) meta[0] = s_cnt[255];
}

// ---------------- fused QKV projection GEMM + V-transpose epilogue (k_vt folded in) -----
__global__ __launch_bounds__(256) void k_qkv(
    const f16* __restrict__ xb, const f16* __restrict__ wqkv,
    const float* __restrict__ bq, const float* __restrict__ bk, const float* __restrict__ bv,
    const int* __restrict__ ridx, const int* __restrict__ meta,
    f16* __restrict__ Qh, f16* __restrict__ Kc, f16* __restrict__ Vtc) {
  __shared__ __attribute__((aligned(16))) f16 lA[128 * 32];
  __shared__ __attribute__((aligned(16))) f16 lB[128 * 32];
  __shared__ __attribute__((aligned(16))) f16 lT[64 * 132];   // V-transpose bounce (16.9KB)
  const int tid = threadIdx.x;
  const int wid = tid >> 6, lane = tid & 63;
  const int hf = lane >> 5, l31 = lane & 31;
  const int wm = wid >> 1, wn = wid & 1;
  const int tn = blockIdx.x;
  const int m0 = blockIdx.y * 128;
  const int mat = tn / 6;
  const int nb = (tn % 6) * 128;
  const int kc = meta[0];
  const int kcp = (kc + 63) & ~63;
  if (mat != 0 && m0 >= kc) return;          // fully-pad K/V tile
  const f16* wbase = wqkv + (size_t)mat * HDIM * HDIM;

  const int ar0 = tid >> 2, ar1 = 64 + (tid >> 2);
  const f16* asrc0;
  const f16* asrc1;
  if (mat == 0) {
    asrc0 = xb + (size_t)(m0 + ar0) * HDIM;
    asrc1 = xb + (size_t)(m0 + ar1) * HDIM;
  } else {
    int g0 = (m0 + ar0 < kc) ? ridx[m0 + ar0] : 0;
    int g1 = (m0 + ar1 < kc) ? ridx[m0 + ar1] : 0;
    asrc0 = xb + (size_t)g0 * HDIM;
    asrc1 = xb + (size_t)g1 * HDIM;
  }
  const int slot = tid & 3;
  const int gs0 = slot ^ swz4(ar0);
  const int gs1 = slot ^ swz4(ar1);

  f32x16 acc[2][2] = {};

  for (int k0 = 0; k0 < HDIM; k0 += 32) {
    async_copy16((const char*)(asrc0 + k0) + gs0 * 16, (char*)lA + (wid * 64) * 16);
    async_copy16((const char*)(asrc1 + k0) + gs1 * 16, (char*)lA + (256 + wid * 64) * 16);
    async_copy16((const char*)(wbase + (size_t)(nb + ar0) * HDIM + k0) + gs0 * 16,
                 (char*)lB + (wid * 64) * 16);
    async_copy16((const char*)(wbase + (size_t)(nb + ar1) * HDIM + k0) + gs1 * 16,
                 (char*)lB + (256 + wid * 64) * 16);
    __syncthreads();
    #pragma unroll
    for (int kk = 0; kk < 2; ++kk) {
      f16x8 af[2], bf[2];
      #pragma unroll
      for (int mi = 0; mi < 2; ++mi) {
        int row = wm * 64 + mi * 32 + l31;
        af[mi] = *(const f16x8*)&lA[row * 32 + (((kk * 2 + hf) ^ swz4(row)) * 8)];
      }
      #pragma unroll
      for (int ni = 0; ni < 2; ++ni) {
        int row = wn * 64 + ni * 32 + l31;
        bf[ni] = *(const f16x8*)&lB[row * 32 + (((kk * 2 + hf) ^ swz4(row)) * 8)];
      }
      #pragma unroll
      for (int mi = 0; mi < 2; ++mi)
        #pragma unroll
        for (int ni = 0; ni < 2; ++ni)
          acc[mi][ni] = __builtin_amdgcn_mfma_f32_32x32x16_f16(af[mi], bf[ni], acc[mi][ni], 0, 0, 0);
    }
    __syncthreads();
  }

  if (mat == 2) {
    // ---- fused V epilogue: transpose+permute to Vtc[h][d][p] via lT ----
    const float* bias = bv;
    #pragma unroll
    for (int pass = 0; pass < 2; ++pass) {     // pass == head_local == wn
      __syncthreads();
      if (wn == pass) {
        #pragma unroll
        for (int ni = 0; ni < 2; ++ni) {
          const int n = nb + wn * 64 + ni * 32 + l31;
          const float bn = bias[n];
          const int dloc = ni * 32 + l31;
          #pragma unroll
          for (int mi = 0; mi < 2; ++mi) {
            #pragma unroll
            for (int rg = 0; rg < 4; ++rg) {   // 4 consecutive s per group
              const int sbase = wm * 64 + mi * 32 + 8 * rg + 4 * hf;
              f16x4 v4;
              #pragma unroll
              for (int j = 0; j < 4; ++j) {
                const int s = m0 + sbase + j;
                v4[j] = (s < kc) ? (f16)(acc[mi][ni][rg * 4 + j] + bn) : (f16)0.f;
              }
              *(f16x4*)&lT[dloc * 132 + sbase] = v4;
            }
          }
        }
      }
      __syncthreads();
      const int headg = (nb >> 6) + pass;
      // 64 d x 16 chunks of 8 keys, k_vt's within-16 bit-2<->3 swap:
      for (int u = tid; u < 1024; u += 256) {
        const int d = u >> 4, p8 = u & 15;
        const int base16 = (p8 >> 1) * 16, half = p8 & 1;
        f16x4 lo = *(const f16x4*)&lT[d * 132 + base16 + half * 4];
        f16x4 hi = *(const f16x4*)&lT[d * 132 + base16 + 8 + half * 4];
        f16x8 o;
        o[0] = lo[0]; o[1] = lo[1]; o[2] = lo[2]; o[3] = lo[3];
        o[4] = hi[0]; o[5] = hi[1]; o[6] = hi[2]; o[7] = hi[3];
        *(f16x8*)&Vtc[((size_t)headg * DHEAD + d) * S_LEN + m0 + p8 * 8] = o;
      }
    }
    return;
  }

  const float* bias = (mat == 0) ? bq : bk;
  const float qscale = 0.125f * 1.44269504088896341f;  // 1/sqrt(64) * log2(e)
  #pragma unroll
  for (int mi = 0; mi < 2; ++mi) {
    #pragma unroll
    for (int ni = 0; ni < 2; ++ni) {
      int n = nb + wn * 64 + ni * 32 + l31;
      int head = n >> 6, d = n & 63;
      float b = bias[n];
      #pragma unroll
      for (int reg = 0; reg < 16; ++reg) {
        int s = m0 + wm * 64 + mi * 32 + (reg & 3) + 8 * (reg >> 2) + 4 * hf;
        float val = acc[mi][ni][reg] + b;
        if (mat == 0) {
          Qh[((size_t)head * S_LEN + s) * DHEAD + d] = (f16)(val * qscale);
        } else if (s < kc) {
          Kc[((size_t)head * S_LEN + s) * DHEAD + d] = (f16)val;
        } else if (s < kcp) {
          Kc[((size_t)head * S_LEN + s) * DHEAD + d] = (f16)0.f;   // K pad rows -> P=1
        }
      }
    }
  }
}

// ---------------- flash attention: single-split + cross-phase ILP within the wave --------
// vs R10 (52-54us, MfmaUtil 20%, waves idle ~75% on the serial QK->exp->PV chain at only
// 1.5 waves/SIMD): restructure the tile body so independent chains overlap IN the wave:
// QK0+QK1 issued back-to-back (QK1 fills QK0's MFMA dep latency), exp0 after (sA long
// done), then PV0 issue -> exp1 runs in PV0's MFMA shadow -> PV1. Costs +32 live VGPR
// (~120 total) -- safe: launch_bounds(128,2) caps at 256 (R5's spill was a 170-cap).
__global__ __launch_bounds__(128, 2) void k_attn(
    const f16* __restrict__ Qh, const f16* __restrict__ Kc, const f16* __restrict__ Vtc,
    const int* __restrict__ meta, f16* __restrict__ PO) {
  __shared__ __attribute__((aligned(16))) f16 lK[2][64 * 64];   // [buf][key][d] swizzled
  __shared__ __attribute__((aligned(16))) f16 lV[2][64 * 64];   // [buf][d][rho] swizzled
  __shared__ float lil[64];                                     // per-query 1/l
  const int tid = threadIdx.x;            // 0..127
  const int wid = tid >> 6, lane = tid & 63;
  const int hf = lane >> 5, l31 = lane & 31, r7 = l31 & 7;

  // XCD head-clustering: 768 blocks, 96 contiguous work units per XCD.
  const int lid = blockIdx.x;
  const int w = ((lid & 7) * 96) + (lid >> 3);
  const int head = w >> 6;
  const int q0 = (w & 63) * 64 + wid * 32;   // wave's 32-query base

  const int kc = meta[0];
  const int nkt = (kc + 63) >> 6;

  const f16* Qp = Qh + ((size_t)head * S_LEN + q0 + l31) * DHEAD;
  f16x8 qf[4];
  #pragma unroll
  for (int dc = 0; dc < 4; ++dc) qf[dc] = *(const f16x8*)(Qp + dc * 16 + hf * 8);

  f32x16 accO[2] = {};
  float ls0 = 0.f, ls1 = 0.f, ls2 = 0.f, ls3 = 0.f;

  const char* kbase = (const char*)(Kc + (size_t)head * S_LEN * DHEAD);
  const char* vbase = (const char*)(Vtc + (size_t)head * DHEAD * S_LEN);

  const int crow = tid >> 3, cslot = tid & 7;
  const int gsc = cslot ^ (crow & 7);

  auto stage = [&](int t, int buf) {
    const int j0 = t * 64;
    #pragma unroll
    for (int it = 0; it < 4; ++it) {
      const int row = it * 16 + crow;
      async_copy16(kbase + (size_t)(j0 + row) * 128 + gsc * 16,
                   (char*)&lK[buf][0] + (it * 128 + wid * 64) * 16);
      async_copy16(vbase + (size_t)row * (S_LEN * 2) + (size_t)j0 * 2 + gsc * 16,
                   (char*)&lV[buf][0] + (it * 128 + wid * 64) * 16);
    }
  };

  int cur = 0;
  stage(0, 0);
  __syncthreads();

  for (int t = 0; t < nkt; ++t) {
    const bool more = (t + 1 < nkt);
    if (more) stage(t + 1, cur ^ 1);

    // ---- QK both halves: 2 independent MFMA chains issued back-to-back ----
    f16x8 af0[4], af1[4];
    #pragma unroll
    for (int dc = 0; dc < 4; ++dc) {
      af0[dc] = *(const f16x8*)&lK[cur][l31 * 64 + ((((dc << 1) | hf) ^ r7) * 8)];
      af1[dc] = *(const f16x8*)&lK[cur][(32 + l31) * 64 + ((((dc << 1) | hf) ^ r7) * 8)];
    }
    f32x16 sA = {}, sB = {};
    #pragma unroll
    for (int dc = 0; dc < 4; ++dc) {
      sA = __builtin_amdgcn_mfma_f32_32x32x16_f16(af0[dc], qf[dc], sA, 0, 0, 0);
      sB = __builtin_amdgcn_mfma_f32_32x32x16_f16(af1[dc], qf[dc], sB, 0, 0, 0);
    }

    // ---- exp A (sA ready: 8 MFMAs issued since its chain ended) ----
    f16x8 pfA[2];
    #pragma unroll
    for (int u = 0; u < 16; ++u) {
      sA[u] = fast_exp2(sA[u]);
      if (u & 1) ls1 += sA[u]; else ls0 += sA[u];
    }
    #pragma unroll
    for (int cc = 0; cc < 2; ++cc)
      #pragma unroll
      for (int u = 0; u < 8; ++u) pfA[cc][u] = (f16)sA[8 * cc + u];

    // ---- PV A issue (c2 = 0,1); exp B runs in its MFMA shadow ----
    #pragma unroll
    for (int cc = 0; cc < 2; ++cc) {
      #pragma unroll
      for (int dh = 0; dh < 2; ++dh) {
        const int vrow = dh * 32 + l31;
        f16x8 vf = *(const f16x8*)&lV[cur][vrow * 64 + ((((cc << 1) | hf) ^ r7) * 8)];
        accO[dh] = __builtin_amdgcn_mfma_f32_32x32x16_f16(pfA[cc], vf, accO[dh], 0, 0, 0);
      }
    }

    f16x8 pfB[2];
    #pragma unroll
    for (int u = 0; u < 16; ++u) {
      sB[u] = fast_exp2(sB[u]);
      if (u & 1) ls3 += sB[u]; else ls2 += sB[u];
    }
    #pragma unroll
    for (int cc = 0; cc < 2; ++cc)
      #pragma unroll
      for (int u = 0; u < 8; ++u) pfB[cc][u] = (f16)sB[8 * cc + u];

    // ---- PV B (c2 = 2,3) ----
    #pragma unroll
    for (int cc = 0; cc < 2; ++cc) {
      #pragma unroll
      for (int dh = 0; dh < 2; ++dh) {
        const int vrow = dh * 32 + l31;
        f16x8 vf = *(const f16x8*)&lV[cur][vrow * 64 + (((((2 + cc) << 1) | hf) ^ r7) * 8)];
        accO[dh] = __builtin_amdgcn_mfma_f32_32x32x16_f16(pfB[cc], vf, accO[dh], 0, 0, 0);
      }
    }

    if (more) {
      __syncthreads();
      cur ^= 1;
    }
  }

  float lsum = (ls0 + ls1) + (ls2 + ls3);
  lsum += __shfl_xor(lsum, 32);              // fold hf halves
  lsum -= (float)(nkt * 64 - kc);            // pad keys (zero K rows) contribute exp=1
  if (hf == 0) lil[wid * 32 + l31] = 1.0f / lsum;
  __syncthreads();                           // publishes lil; all lK/lV reads done

  // normalized, coalesced PO store via LDS bounce (reuse dead lK; 4KB per wave)
  f16* ost = (f16*)lK + wid * 2048;
  #pragma unroll
  for (int dh = 0; dh < 2; ++dh)
    #pragma unroll
    for (int reg = 0; reg < 16; ++reg) {
      int row = (reg & 3) + 8 * (reg >> 2) + 4 * hf;
      ost[row * 64 + dh * 32 + l31] = (f16)(accO[dh][reg] * lil[wid * 32 + row]);
    }
  #pragma unroll
  for (int p = 0; p < 4; ++p) {
    int row = p * 8 + (lane >> 3), sl = lane & 7;
    f16x8 v = *(const f16x8*)&ost[row * 64 + sl * 8];
    *(f16x8*)&PO[((size_t)head * S_LEN + q0 + row) * DHEAD + sl * 8] = v;
  }
}

// ---------------- output projection GEMM: single normalized PO, all-async staging --------
__global__ __launch_bounds__(256) void k_out(
    const f16* __restrict__ PO, const f16* __restrict__ wo,
    const float* __restrict__ bo, float* __restrict__ out) {
  __shared__ __attribute__((aligned(16))) f16 lA[128 * 64];   // 16KB
  __shared__ __attribute__((aligned(16))) f16 lB[64 * 64];    // 8KB
  const int tid = threadIdx.x;
  const int wid = tid >> 6, lane = tid & 63;
  const int hf = lane >> 5, l31 = lane & 31;
  const int wm = wid >> 1, wn = wid & 1;     // 2x2 waves of 64m x 32n
  const int lid = blockIdx.x;
  const int w = ((lid & 7) * 48) + (lid >> 3);   // XCD-grouped: 48 units/XCD share m-tiles
  const int nb = (w % 12) * 64;
  const int m0 = (w / 12) * 128;

  f32x16 acc[2] = {};   // [mi]

  for (int head = 0; head < NHEAD; ++head) {   // BK=64 == one head per step
    // A: PO rows (already normalized f16) via async; 1024 chunks
    #pragma unroll
    for (int it = 0; it < 4; ++it) {
      int c = it * 256 + tid;
      int row = c >> 3, slot = c & 7;
      int gs = slot ^ (row & 7);
      async_copy16((const char*)(PO + ((size_t)head * S_LEN + m0 + row) * DHEAD) + gs * 16,
                   (char*)lA + (it * 256 + wid * 64) * 16);
    }
    // B: wo rows (output cols) nb..nb+63, k-range head*64..+64; 512 chunks
    #pragma unroll
    for (int it = 0; it < 2; ++it) {
      int c = it * 256 + tid;
      int row = c >> 3, slot = c & 7;
      int gs = slot ^ (row & 7);
      async_copy16((const char*)(wo + (size_t)(nb + row) * HDIM + head * 64) + gs * 16,
                   (char*)lB + (it * 256 + wid * 64) * 16);
    }
    __syncthreads();
    #pragma unroll
    for (int kk = 0; kk < 4; ++kk) {
      f16x8 af[2], bf;
      #pragma unroll
      for (int mi = 0; mi < 2; ++mi) {
        int row = wm * 64 + mi * 32 + l31;
        af[mi] = *(const f16x8*)&lA[row * 64 + ((((kk << 1) | hf) ^ (row & 7)) * 8)];
      }
      int rb = wn * 32 + l31;
      bf = *(const f16x8*)&lB[rb * 64 + ((((kk << 1) | hf) ^ (rb & 7)) * 8)];
      #pragma unroll
      for (int mi = 0; mi < 2; ++mi)
        acc[mi] = __builtin_amdgcn_mfma_f32_32x32x16_f16(af[mi], bf, acc[mi], 0, 0, 0);
    }
    __syncthreads();
  }

  const int n = nb + wn * 32 + l31;
  const float b = bo[n];
  #pragma unroll
  for (int mi = 0; mi < 2; ++mi) {
    #pragma unroll
    for (int reg = 0; reg < 16; ++reg) {
      int s = m0 + wm * 64 + mi * 32 + (reg & 3) + 8 * (reg >> 2) + 4 * hf;
      out[(size_t)s * HDIM + n] = acc[mi][reg] + b;
    }
  }
}

extern "C" void kernel_launch(void* const* d_in, const int* in_sizes, int n_in,
                              void* d_out, int out_size, void* d_ws, size_t ws_size,
                              hipStream_t stream) {
  const float* x  = (const float*)d_in[0];
  const float* Wq = (const float*)d_in[1];
  const float* bq = (const float*)d_in[2];
  const float* Wk = (const float*)d_in[3];
  const float* bk = (const float*)d_in[4];
  const float* Wv = (const float*)d_in[5];
  const float* bv = (const float*)d_in[6];
  const float* Wo = (const float*)d_in[7];
  const float* bo = (const float*)d_in[8];
  const int*   mask = (const int*)d_in[9];
  float* out = (float*)d_out;

  char* ws = (char*)d_ws;
  int* meta  = (int*)(ws + OFF_META);
  int* ridx  = (int*)(ws + OFF_RIDX);
  f16* xb    = (f16*)(ws + OFF_XB);
  f16* wqkv  = (f16*)(ws + OFF_WQKV);
  f16* wob   = (f16*)(ws + OFF_WO);
  f16* Qh    = (f16*)(ws + OFF_Q);
  f16* Kc    = (f16*)(ws + OFF_K);
  f16* Vtc   = (f16*)(ws + OFF_VT);
  f16* PO    = (f16*)(ws + OFF_PO);

  k_prep<<<dim3(5377), 256, 0, stream>>>(x, Wq, Wk, Wv, Wo, mask, xb, ridx, meta);
  k_qkv<<<dim3(18, 32), 256, 0, stream>>>(xb, wqkv, bq, bk, bv, ridx, meta, Qh, Kc, Vtc);
  k_attn<<<dim3(768), 128, 0, stream>>>(Qh, Kc, Vtc, meta, PO);
  k_out<<<dim3(384), 256, 0, stream>>>(PO, wob, bo, out);
}